// Round 1
// baseline (6571.272 us; speedup 1.0000x reference)
//
#include <hip/hip_runtime.h>
#include <math.h>

#define BATCHN 256
#define HDIM 512
#define ZDIM 128
#define NGRID 32
#define ABDIM 128
#define IMGSZ 16384   // 128*128
#define ENCIN 2560
#define G3 1536

__device__ __forceinline__ float sigmoidf_(float x){ return 1.0f/(1.0f+expf(-x)); }

// sigmoid of last batch row of reconsts -> s_last[16384]
__global__ void sig_last_k(const float* __restrict__ rec, float* __restrict__ s_last){
    int i = blockIdx.x*256 + threadIdx.x;
    s_last[i] = sigmoidf_(rec[(size_t)(BATCHN-1)*IMGSZ + i]);
}

// p = h_dec @ W^T + b  (5 outputs), then derive filterbank params
// params[b*8+{0..4}] = g_x, g_y, delta, two_sigma_sq, gamma
__global__ void attn_params_k(const float* __restrict__ hdec, const float* __restrict__ W,
                              const float* __restrict__ b, float* __restrict__ params){
    int bb = blockIdx.x; int lane = threadIdx.x;  // 64 threads
    const float* h = hdec + bb*HDIM;
    float p[5];
    #pragma unroll
    for(int i=0;i<5;i++){
        float acc = 0.f;
        for(int k=lane;k<HDIM;k+=64) acc += h[k]*W[i*HDIM+k];
        #pragma unroll
        for(int o=32;o>0;o>>=1) acc += __shfl_down(acc,o);
        p[i] = __shfl(acc,0) + b[i];
    }
    if(lane==0){
        float* o = params + bb*8;
        o[0] = 64.5f*(p[0]+1.0f);            // g_x = 0.5*(A+1)*(gt_x+1)
        o[1] = 64.5f*(p[1]+1.0f);            // g_y
        o[2] = (127.0f/31.0f)*expf(p[3]);    // delta
        o[3] = 2.0f*expf(p[2]);              // two_sigma_sq
        o[4] = expf(p[4]);                   // gamma
    }
}

// F[b,j,p] = exp(-(p-mu)^2/tss) / max(sum_p, eps);  grid.x = 256*32 (b,j), grid.y: 0->Fx, 1->Fy
__global__ void filterbank_k(const float* __restrict__ params, float* __restrict__ Fx, float* __restrict__ Fy){
    int bj = blockIdx.x; int bb = bj>>5; int j = bj&31;
    int p = threadIdx.x;   // 128
    const float* pr = params + bb*8;
    float g = (blockIdx.y==0)? pr[0] : pr[1];
    float delta = pr[2], tss = pr[3];
    float mu = g + ((float)j - 15.5f)*delta;
    float d = (float)p - mu;
    float v = expf(-d*d/tss);
    float s = v;
    #pragma unroll
    for(int o=32;o>0;o>>=1) s += __shfl_down(s,o);
    __shared__ float red[2];
    if((p&63)==0) red[p>>6]=s;
    __syncthreads();
    float tot = red[0]+red[1];
    float* F = (blockIdx.y==0)? Fx : Fy;
    F[(size_t)(bb*NGRID+j)*ABDIM + p] = v / fmaxf(tot, 1e-8f);
}

// per-batch: x_attn = Fy @ img @ Fx^T, xh_attn with img_hat; enc_in = [gamma*x_attn, gamma*xh_attn, h_dec]
__global__ __launch_bounds__(256) void read_attn_k(const float* __restrict__ xf, const float* __restrict__ s_last,
        const float* __restrict__ Fx, const float* __restrict__ Fy, const float* __restrict__ params,
        const float* __restrict__ hdec, float* __restrict__ enc_in){
    __shared__ float sFy[NGRID][ABDIM+1];
    __shared__ float sFx[NGRID][ABDIM+1];
    __shared__ float tmp[NGRID][ABDIM+1];
    int bb = blockIdx.x; int tid = threadIdx.x;
    for(int i=tid;i<NGRID*ABDIM;i+=256){
        sFy[i>>7][i&127] = Fy[(size_t)bb*NGRID*ABDIM + i];
        sFx[i>>7][i&127] = Fx[(size_t)bb*NGRID*ABDIM + i];
    }
    float gamma = params[bb*8+4];
    const float* img = xf + (size_t)bb*IMGSZ;
    __syncthreads();
    int c = tid & 127;
    int j0 = tid >> 7;   // 0 or 1
    for(int pass=0; pass<2; pass++){
        float acc[16];
        #pragma unroll
        for(int i=0;i<16;i++) acc[i]=0.f;
        for(int k=0;k<ABDIM;k++){
            float s = img[k*ABDIM + c];
            if(pass) s -= s_last[k*ABDIM + c];
            #pragma unroll
            for(int i=0;i<16;i++) acc[i] += sFy[j0+2*i][k]*s;
        }
        __syncthreads();   // prior stage2 done reading tmp
        #pragma unroll
        for(int i=0;i<16;i++) tmp[j0+2*i][c] = acc[i];
        __syncthreads();
        #pragma unroll
        for(int it=0; it<4; it++){
            int idx = tid + 256*it;
            int i2 = idx & 31, j = idx >> 5;
            float a = 0.f;
            for(int cc=0; cc<ABDIM; cc++) a += tmp[j][cc]*sFx[i2][cc];
            enc_in[(size_t)bb*ENCIN + pass*1024 + j*NGRID + i2] = gamma*a;
        }
    }
    for(int i=tid;i<HDIM;i+=256) enc_in[(size_t)bb*ENCIN + 2048 + i] = hdec[bb*HDIM + i];
}

// C[M,Nn] = A[M,K] @ W[Nn,K]^T + bias ; 64x64 tile, BK=16, 4x4 microtile, 256 thr
__global__ __launch_bounds__(256) void gemm_nt_k(const float* __restrict__ A, const float* __restrict__ W,
        const float* __restrict__ bias, float* __restrict__ C, int M, int Nn, int K){
    __shared__ float As[16][68];
    __shared__ float Bs[16][68];
    int tid = threadIdx.x;
    int row0 = blockIdx.y*64, col0 = blockIdx.x*64;
    int tx = tid & 15, ty = tid >> 4;
    int lr = tid >> 2, lc = (tid & 3)*4;
    float acc[4][4] = {{0.f}};
    for(int k0=0;k0<K;k0+=16){
        float4 av = *(const float4*)(A + (size_t)(row0+lr)*K + k0 + lc);
        float4 wv = *(const float4*)(W + (size_t)(col0+lr)*K + k0 + lc);
        As[lc+0][lr]=av.x; As[lc+1][lr]=av.y; As[lc+2][lr]=av.z; As[lc+3][lr]=av.w;
        Bs[lc+0][lr]=wv.x; Bs[lc+1][lr]=wv.y; Bs[lc+2][lr]=wv.z; Bs[lc+3][lr]=wv.w;
        __syncthreads();
        #pragma unroll
        for(int kk=0;kk<16;kk++){
            float4 a4 = *(const float4*)&As[kk][ty*4];
            float4 b4 = *(const float4*)&Bs[kk][tx*4];
            float av_[4] = {a4.x,a4.y,a4.z,a4.w};
            float bv_[4] = {b4.x,b4.y,b4.z,b4.w};
            #pragma unroll
            for(int i=0;i<4;i++)
                #pragma unroll
                for(int jj=0;jj<4;jj++) acc[i][jj] += av_[i]*bv_[jj];
        }
        __syncthreads();
    }
    float4 bb4 = *(const float4*)&bias[col0 + tx*4];
    float bv_[4] = {bb4.x, bb4.y, bb4.z, bb4.w};
    #pragma unroll
    for(int i=0;i<4;i++){
        float4 o;
        o.x = acc[i][0]+bv_[0]; o.y = acc[i][1]+bv_[1];
        o.z = acc[i][2]+bv_[2]; o.w = acc[i][3]+bv_[3];
        *(float4*)(C + (size_t)(row0+ty*4+i)*Nn + col0 + tx*4) = o;
    }
}

// h = (1-z)*n + z*h  in place; gi/gh are [256,1536]
__global__ void gru_combine_k(const float* __restrict__ gi, const float* __restrict__ gh, float* __restrict__ h){
    int idx = blockIdx.x*256 + threadIdx.x;       // 256*512
    int bb = idx >> 9, j = idx & 511;
    const float* gib = gi + (size_t)bb*G3;
    const float* ghb = gh + (size_t)bb*G3;
    float r = sigmoidf_(gib[j] + ghb[j]);
    float z = sigmoidf_(gib[512+j] + ghb[512+j]);
    float n = tanhf(gib[1024+j] + r*ghb[1024+j]);
    h[idx] = (1.f - z)*n + z*h[idx];
}

// z = (h@Wmu^T+bmu) + eps_t * exp(h@Wls^T+bls)
__global__ void z_k(const float* __restrict__ henc, const float* __restrict__ Wmu, const float* __restrict__ bmu,
        const float* __restrict__ Wls, const float* __restrict__ bls, const float* __restrict__ eps_t,
        float* __restrict__ z){
    int bb = blockIdx.x, j = threadIdx.x;  // 128 threads
    const float* h = henc + (size_t)bb*HDIM;
    const float* wm = Wmu + (size_t)j*HDIM;
    const float* wl = Wls + (size_t)j*HDIM;
    float am=0.f, al=0.f;
    for(int k=0;k<HDIM;k++){ float hv=h[k]; am += hv*wm[k]; al += hv*wl[k]; }
    float mu = am + bmu[j];
    float sg = expf(al + bls[j]);
    z[(size_t)bb*ZDIM + j] = mu + eps_t[(size_t)bb*ZDIM + j]*sg;
}

// rec += (Fyw^T @ w @ Fxw)/gamma  per batch
__global__ __launch_bounds__(256) void write_apply_k(const float* __restrict__ wbuf, const float* __restrict__ Fx,
        const float* __restrict__ Fy, const float* __restrict__ params, float* __restrict__ rec){
    __shared__ float sFy[NGRID][ABDIM+1];
    __shared__ float sFx[NGRID][ABDIM+1];
    __shared__ float sw[NGRID][NGRID+1];
    __shared__ float t[ABDIM][NGRID+1];
    int bb = blockIdx.x, tid = threadIdx.x;
    for(int i=tid;i<NGRID*ABDIM;i+=256){
        sFy[i>>7][i&127] = Fy[(size_t)bb*NGRID*ABDIM + i];
        sFx[i>>7][i&127] = Fx[(size_t)bb*NGRID*ABDIM + i];
    }
    for(int i=tid;i<NGRID*NGRID;i+=256) sw[i>>5][i&31] = wbuf[(size_t)bb*1024 + i];
    float invg = 1.0f / params[bb*8+4];
    __syncthreads();
    #pragma unroll
    for(int it=0; it<16; it++){
        int idx = tid + 256*it;
        int i2 = idx & 31, p = idx >> 5;
        float acc = 0.f;
        #pragma unroll
        for(int j=0;j<NGRID;j++) acc += sFy[j][p]*sw[j][i2];
        t[p][i2] = acc;
    }
    __syncthreads();
    for(int it=0; it<64; it++){
        int idx = tid + 256*it;
        int q = idx & 127, p = idx >> 7;
        float acc = 0.f;
        #pragma unroll
        for(int i=0;i<NGRID;i++) acc += t[p][i]*sFx[i][q];
        rec[(size_t)bb*IMGSZ + p*ABDIM + q] += acc*invg;
    }
}

__global__ void sigmoid_all_k(float* __restrict__ rec){
    int i = blockIdx.x*256 + threadIdx.x;
    rec[i] = sigmoidf_(rec[i]);
}

extern "C" void kernel_launch(void* const* d_in, const int* in_sizes, int n_in,
                              void* d_out, int out_size, void* d_ws, size_t ws_size,
                              hipStream_t stream) {
    const float* x        = (const float*)d_in[0];
    const float* eps      = (const float*)d_in[1];
    const float* W_ih_enc = (const float*)d_in[2];
    const float* W_hh_enc = (const float*)d_in[3];
    const float* b_ih_enc = (const float*)d_in[4];
    const float* b_hh_enc = (const float*)d_in[5];
    const float* W_ih_dec = (const float*)d_in[6];
    const float* W_hh_dec = (const float*)d_in[7];
    const float* b_ih_dec = (const float*)d_in[8];
    const float* b_hh_dec = (const float*)d_in[9];
    const float* W_mu     = (const float*)d_in[10];
    const float* b_mu     = (const float*)d_in[11];
    const float* W_ls     = (const float*)d_in[12];
    const float* b_ls     = (const float*)d_in[13];
    const float* W_wr     = (const float*)d_in[14];
    const float* b_wr     = (const float*)d_in[15];
    const float* W_ra     = (const float*)d_in[16];
    const float* b_ra     = (const float*)d_in[17];
    const float* W_wa     = (const float*)d_in[18];
    const float* b_wa     = (const float*)d_in[19];

    float* rec = (float*)d_out;                       // reconsts lives in d_out

    float* ws = (float*)d_ws;
    float* h_enc  = ws;               ws += BATCHN*HDIM;          // 131072
    float* h_dec  = ws;               ws += BATCHN*HDIM;          // 131072
    float* s_last = ws;               ws += IMGSZ;                // 16384
    float* params = ws;               ws += BATCHN*8;             // 2048
    float* Fx     = ws;               ws += BATCHN*NGRID*ABDIM;   // 1048576
    float* Fy     = ws;               ws += BATCHN*NGRID*ABDIM;   // 1048576
    float* enc_in = ws;               ws += BATCHN*ENCIN;         // 655360
    float* gi     = ws;               ws += BATCHN*G3;            // 393216
    float* gh     = ws;               ws += BATCHN*G3;            // 393216
    float* zbuf   = ws;               ws += BATCHN*ZDIM;          // 32768
    float* wbuf   = ws;               ws += BATCHN*1024;          // 262144

    hipMemsetAsync(rec,   0, (size_t)BATCHN*IMGSZ*sizeof(float), stream);
    hipMemsetAsync(h_enc, 0, (size_t)BATCHN*HDIM*sizeof(float), stream);
    hipMemsetAsync(h_dec, 0, (size_t)BATCHN*HDIM*sizeof(float), stream);

    for(int t=0;t<16;t++){
        sig_last_k<<<IMGSZ/256,256,0,stream>>>(rec, s_last);
        // ---- read attention ----
        attn_params_k<<<BATCHN,64,0,stream>>>(h_dec, W_ra, b_ra, params);
        filterbank_k<<<dim3(BATCHN*NGRID,2),128,0,stream>>>(params, Fx, Fy);
        read_attn_k<<<BATCHN,256,0,stream>>>(x, s_last, Fx, Fy, params, h_dec, enc_in);
        // ---- encoder GRU ----
        gemm_nt_k<<<dim3(G3/64, BATCHN/64),256,0,stream>>>(enc_in, W_ih_enc, b_ih_enc, gi, BATCHN, G3, ENCIN);
        gemm_nt_k<<<dim3(G3/64, BATCHN/64),256,0,stream>>>(h_enc, W_hh_enc, b_hh_enc, gh, BATCHN, G3, HDIM);
        gru_combine_k<<<BATCHN*HDIM/256,256,0,stream>>>(gi, gh, h_enc);
        // ---- z sample ----
        z_k<<<BATCHN,128,0,stream>>>(h_enc, W_mu, b_mu, W_ls, b_ls, eps + (size_t)t*BATCHN*ZDIM, zbuf);
        // ---- decoder GRU ----
        gemm_nt_k<<<dim3(G3/64, BATCHN/64),256,0,stream>>>(zbuf, W_ih_dec, b_ih_dec, gi, BATCHN, G3, ZDIM);
        gemm_nt_k<<<dim3(G3/64, BATCHN/64),256,0,stream>>>(h_dec, W_hh_dec, b_hh_dec, gh, BATCHN, G3, HDIM);
        gru_combine_k<<<BATCHN*HDIM/256,256,0,stream>>>(gi, gh, h_dec);
        // ---- write attention ----
        attn_params_k<<<BATCHN,64,0,stream>>>(h_dec, W_wa, b_wa, params);
        filterbank_k<<<dim3(BATCHN*NGRID,2),128,0,stream>>>(params, Fx, Fy);
        gemm_nt_k<<<dim3(1024/64, BATCHN/64),256,0,stream>>>(h_dec, W_wr, b_wr, wbuf, BATCHN, 1024, HDIM);
        write_apply_k<<<BATCHN,256,0,stream>>>(wbuf, Fx, Fy, params, rec);
    }
    sigmoid_all_k<<<BATCHN*IMGSZ/256,256,0,stream>>>(rec);
}

// Round 2
// 3867.619 us; speedup vs baseline: 1.6990x; 1.6990x over previous
//
#include <hip/hip_runtime.h>
#include <math.h>

#define BATCHN 256
#define HDIM 512
#define ZDIM 128
#define NGRID 32
#define ABDIM 128
#define IMGSZ 16384   // 128*128
#define ENCIN 2560
#define G3 1536
#define SPLITK 4

__device__ __forceinline__ float sigmoidf_(float x){ return 1.0f/(1.0f+expf(-x)); }

__global__ void init_slast_k(float* __restrict__ s_last){
    int i = blockIdx.x*256 + threadIdx.x;
    s_last[i] = 0.5f;   // sigmoid(0)
}

// ---- helper: compute attention params inside a per-batch block (256 threads) ----
// result broadcast via LDS pp[8]: gx, gy, tss, delta, gamma
__device__ __forceinline__ void attn_params_dev(const float* __restrict__ h,
        const float* __restrict__ W, const float* __restrict__ bvec,
        float* red5 /*[5*4]*/, float* pp /*[8]*/, int tid){
    float accp[5];
    #pragma unroll
    for(int i=0;i<5;i++) accp[i]=0.f;
    for(int k=tid;k<HDIM;k+=256){
        float hv = h[k];
        #pragma unroll
        for(int i=0;i<5;i++) accp[i] += hv*W[i*HDIM+k];
    }
    int wv = tid>>6;
    #pragma unroll
    for(int i=0;i<5;i++){
        float a = accp[i];
        #pragma unroll
        for(int o=32;o>0;o>>=1) a += __shfl_down(a,o);
        if((tid&63)==0) red5[i*4+wv]=a;
    }
    __syncthreads();
    if(tid<5){
        float s = red5[tid*4+0]+red5[tid*4+1]+red5[tid*4+2]+red5[tid*4+3] + bvec[tid];
        pp[tid]=s;
    }
    __syncthreads();
}

// fill normalized filterbanks into LDS sFx/sFy [32][129]
__device__ __forceinline__ void fill_filterbanks_dev(float (*sFx)[ABDIM+1], float (*sFy)[ABDIM+1],
        const float* pp, int tid){
    float gx = 64.5f*(pp[0]+1.0f);
    float gy = 64.5f*(pp[1]+1.0f);
    float tss = 2.0f*expf(pp[2]);
    float delta = (127.0f/31.0f)*expf(pp[3]);
    int rr = tid>>2;        // 0..63 : 0..31 -> Fx rows, 32..63 -> Fy rows
    int q  = tid&3;         // quarter of the 128 pixels
    int j  = rr&31;
    bool isY = rr>=32;
    float mu = (isY?gy:gx) + ((float)j-15.5f)*delta;
    float* rowp = isY? &sFy[j][0] : &sFx[j][0];
    float s = 0.f;
    #pragma unroll
    for(int i=0;i<32;i++){
        float d = (float)(q*32+i)-mu;
        float v = expf(-d*d/tss);
        rowp[q*32+i]=v; s+=v;
    }
    s += __shfl_xor(s,1);
    s += __shfl_xor(s,2);
    float inv = 1.0f/fmaxf(s,1e-8f);
    #pragma unroll
    for(int i=0;i<32;i++) rowp[q*32+i]*=inv;
    __syncthreads();
}

// per-batch: params+filterbank+read-attention; enc_in = [g*x_attn, g*xh_attn, h_dec]
__global__ __launch_bounds__(256) void read_attn_k(const float* __restrict__ xf, const float* __restrict__ s_last,
        const float* __restrict__ hdec, const float* __restrict__ W_ra, const float* __restrict__ b_ra,
        float* __restrict__ enc_in){
    __shared__ float sFy[NGRID][ABDIM+1];
    __shared__ float sFx[NGRID][ABDIM+1];
    __shared__ float tmp[NGRID][ABDIM+1];
    __shared__ float red5[20];
    __shared__ float pp[8];
    int bb = blockIdx.x; int tid = threadIdx.x;
    const float* h = hdec + bb*HDIM;
    attn_params_dev(h, W_ra, b_ra, red5, pp, tid);
    float gamma = expf(pp[4]);
    fill_filterbanks_dev(sFx, sFy, pp, tid);
    const float* img = xf + (size_t)bb*IMGSZ;
    int c = tid & 127;
    int j0 = tid >> 7;   // 0 or 1
    for(int pass=0; pass<2; pass++){
        float acc[16];
        #pragma unroll
        for(int i=0;i<16;i++) acc[i]=0.f;
        for(int k=0;k<ABDIM;k++){
            float s = img[k*ABDIM + c];
            if(pass) s -= s_last[k*ABDIM + c];
            #pragma unroll
            for(int i=0;i<16;i++) acc[i] += sFy[j0+2*i][k]*s;
        }
        __syncthreads();
        #pragma unroll
        for(int i=0;i<16;i++) tmp[j0+2*i][c] = acc[i];
        __syncthreads();
        #pragma unroll
        for(int it=0; it<4; it++){
            int idx = tid + 256*it;
            int i2 = idx & 31, j = idx >> 5;
            float a = 0.f;
            for(int cc=0; cc<ABDIM; cc++) a += tmp[j][cc]*sFx[i2][cc];
            enc_in[(size_t)bb*ENCIN + pass*1024 + j*NGRID + i2] = gamma*a;
        }
        __syncthreads();
    }
    for(int i=tid;i<HDIM;i+=256) enc_in[(size_t)bb*ENCIN + 2048 + i] = hdec[bb*HDIM + i];
}

// split-K GEMM for GRU: Pi[s] += A1@W1^T chunk, Ph[s] += A2@W2^T chunk
// grid (Nn/64, 4, SPLITK); 64x64 tile, BK=16, 4x4 microtile
__global__ __launch_bounds__(256) void gemm_gru_splitk(const float* __restrict__ A1, const float* __restrict__ W1, int K1,
        const float* __restrict__ A2, const float* __restrict__ W2, int K2,
        float* __restrict__ Pi, float* __restrict__ Ph, int Nn){
    __shared__ float As[16][68];
    __shared__ float Bs[16][68];
    int tid = threadIdx.x;
    int row0 = blockIdx.y*64, col0 = blockIdx.x*64;
    int s = blockIdx.z;
    int tx = tid & 15, ty = tid >> 4;
    int lr = tid >> 2, lc = (tid & 3)*4;
    int ch1 = K1/SPLITK, ch2 = K2/SPLITK;
    float acc_i[4][4] = {{0.f}};
    float acc_h[4][4] = {{0.f}};
    for(int k0=s*ch1; k0<s*ch1+ch1; k0+=16){
        float4 av = *(const float4*)(A1 + (size_t)(row0+lr)*K1 + k0 + lc);
        float4 wv = *(const float4*)(W1 + (size_t)(col0+lr)*K1 + k0 + lc);
        As[lc+0][lr]=av.x; As[lc+1][lr]=av.y; As[lc+2][lr]=av.z; As[lc+3][lr]=av.w;
        Bs[lc+0][lr]=wv.x; Bs[lc+1][lr]=wv.y; Bs[lc+2][lr]=wv.z; Bs[lc+3][lr]=wv.w;
        __syncthreads();
        #pragma unroll
        for(int kk=0;kk<16;kk++){
            float4 a4 = *(const float4*)&As[kk][ty*4];
            float4 b4 = *(const float4*)&Bs[kk][tx*4];
            float av_[4] = {a4.x,a4.y,a4.z,a4.w};
            float bv_[4] = {b4.x,b4.y,b4.z,b4.w};
            #pragma unroll
            for(int i=0;i<4;i++)
                #pragma unroll
                for(int jj=0;jj<4;jj++) acc_i[i][jj] += av_[i]*bv_[jj];
        }
        __syncthreads();
    }
    if(K2>0){
        for(int k0=s*ch2; k0<s*ch2+ch2; k0+=16){
            float4 av = *(const float4*)(A2 + (size_t)(row0+lr)*K2 + k0 + lc);
            float4 wv = *(const float4*)(W2 + (size_t)(col0+lr)*K2 + k0 + lc);
            As[lc+0][lr]=av.x; As[lc+1][lr]=av.y; As[lc+2][lr]=av.z; As[lc+3][lr]=av.w;
            Bs[lc+0][lr]=wv.x; Bs[lc+1][lr]=wv.y; Bs[lc+2][lr]=wv.z; Bs[lc+3][lr]=wv.w;
            __syncthreads();
            #pragma unroll
            for(int kk=0;kk<16;kk++){
                float4 a4 = *(const float4*)&As[kk][ty*4];
                float4 b4 = *(const float4*)&Bs[kk][tx*4];
                float av_[4] = {a4.x,a4.y,a4.z,a4.w};
                float bv_[4] = {b4.x,b4.y,b4.z,b4.w};
                #pragma unroll
                for(int i=0;i<4;i++)
                    #pragma unroll
                    for(int jj=0;jj<4;jj++) acc_h[i][jj] += av_[i]*bv_[jj];
            }
            __syncthreads();
        }
    }
    #pragma unroll
    for(int i=0;i<4;i++){
        float4 o;
        o.x=acc_i[i][0]; o.y=acc_i[i][1]; o.z=acc_i[i][2]; o.w=acc_i[i][3];
        *(float4*)(Pi + ((size_t)s*BATCHN + row0+ty*4+i)*Nn + col0 + tx*4) = o;
    }
    if(K2>0){
        #pragma unroll
        for(int i=0;i<4;i++){
            float4 o;
            o.x=acc_h[i][0]; o.y=acc_h[i][1]; o.z=acc_h[i][2]; o.w=acc_h[i][3];
            *(float4*)(Ph + ((size_t)s*BATCHN + row0+ty*4+i)*Nn + col0 + tx*4) = o;
        }
    }
}

// reduce partials + biases + GRU gates; h = (1-z)*n + z*h
__global__ void gru_combine_k(const float* __restrict__ Pi, const float* __restrict__ Ph,
        const float* __restrict__ bi, const float* __restrict__ bh, float* __restrict__ h){
    int idx = blockIdx.x*256 + threadIdx.x;       // 256*512
    int bb = idx >> 9, j = idx & 511;
    float gi_r=0,gi_z=0,gi_n=0,gh_r=0,gh_z=0,gh_n=0;
    #pragma unroll
    for(int s=0;s<SPLITK;s++){
        size_t base = ((size_t)s*BATCHN + bb)*G3 + j;
        gi_r += Pi[base]; gi_z += Pi[base+512]; gi_n += Pi[base+1024];
        gh_r += Ph[base]; gh_z += Ph[base+512]; gh_n += Ph[base+1024];
    }
    gi_r += bi[j];      gh_r += bh[j];
    gi_z += bi[512+j];  gh_z += bh[512+j];
    gi_n += bi[1024+j]; gh_n += bh[1024+j];
    float r = sigmoidf_(gi_r + gh_r);
    float z = sigmoidf_(gi_z + gh_z);
    float n = tanhf(gi_n + r*gh_n);
    h[idx] = (1.f - z)*n + z*h[idx];
}

// z = (h@Wmu^T+bmu) + eps_t * exp(h@Wls^T+bls); block per batch, wave per output group
__global__ __launch_bounds__(256) void z_k(const float* __restrict__ henc, const float* __restrict__ Wmu,
        const float* __restrict__ bmu, const float* __restrict__ Wls, const float* __restrict__ bls,
        const float* __restrict__ eps_t, float* __restrict__ z){
    __shared__ float hs[HDIM];
    int bb = blockIdx.x, tid = threadIdx.x;
    int lane = tid&63, wv = tid>>6;
    for(int i=tid;i<HDIM;i+=256) hs[i]=henc[(size_t)bb*HDIM+i];
    __syncthreads();
    for(int it=0; it<32; ++it){
        int j = wv*32 + it;
        float am=0.f, al=0.f;
        for(int k=lane;k<HDIM;k+=64){
            float hv=hs[k];
            am += hv*Wmu[(size_t)j*HDIM+k];
            al += hv*Wls[(size_t)j*HDIM+k];
        }
        #pragma unroll
        for(int o=32;o>0;o>>=1){ am += __shfl_down(am,o); al += __shfl_down(al,o); }
        if(lane==0){
            float mu = am + bmu[j];
            float sg = expf(al + bls[j]);
            z[(size_t)bb*ZDIM + j] = mu + eps_t[(size_t)bb*ZDIM + j]*sg;
        }
    }
}

// write path: params+filterbank+reduce(Pw)+apply; also refresh s_last from batch 255
__global__ __launch_bounds__(256) void write_apply_k(const float* __restrict__ Pw, const float* __restrict__ b_wr,
        const float* __restrict__ hdec, const float* __restrict__ W_wa, const float* __restrict__ b_wa,
        float* __restrict__ rec, float* __restrict__ s_last){
    __shared__ float sFy[NGRID][ABDIM+1];
    __shared__ float sFx[NGRID][ABDIM+1];
    __shared__ float sw[NGRID][NGRID+1];
    __shared__ float t[ABDIM][NGRID+1];
    __shared__ float red5[20];
    __shared__ float pp[8];
    int bb = blockIdx.x, tid = threadIdx.x;
    const float* h = hdec + bb*HDIM;
    attn_params_dev(h, W_wa, b_wa, red5, pp, tid);
    float invg = expf(-pp[4]);
    fill_filterbanks_dev(sFx, sFy, pp, tid);
    for(int i=tid;i<NGRID*NGRID;i+=256){
        float a = b_wr[i];
        #pragma unroll
        for(int s=0;s<SPLITK;s++) a += Pw[((size_t)s*BATCHN + bb)*1024 + i];
        sw[i>>5][i&31] = a;
    }
    __syncthreads();
    #pragma unroll
    for(int it=0; it<16; it++){
        int idx = tid + 256*it;
        int i2 = idx & 31, p = idx >> 5;
        float acc = 0.f;
        #pragma unroll
        for(int j=0;j<NGRID;j++) acc += sFy[j][p]*sw[j][i2];
        t[p][i2] = acc;
    }
    __syncthreads();
    for(int it=0; it<64; it++){
        int idx = tid + 256*it;
        int q = idx & 127, p = idx >> 7;
        float acc = 0.f;
        #pragma unroll
        for(int i=0;i<NGRID;i++) acc += t[p][i]*sFx[i][q];
        float nv = rec[(size_t)bb*IMGSZ + p*ABDIM + q] + acc*invg;
        rec[(size_t)bb*IMGSZ + p*ABDIM + q] = nv;
        if(bb==BATCHN-1) s_last[p*ABDIM + q] = sigmoidf_(nv);
    }
}

__global__ void sigmoid_all_k(float* __restrict__ rec){
    int i = blockIdx.x*256 + threadIdx.x;
    rec[i] = sigmoidf_(rec[i]);
}

extern "C" void kernel_launch(void* const* d_in, const int* in_sizes, int n_in,
                              void* d_out, int out_size, void* d_ws, size_t ws_size,
                              hipStream_t stream) {
    const float* x        = (const float*)d_in[0];
    const float* eps      = (const float*)d_in[1];
    const float* W_ih_enc = (const float*)d_in[2];
    const float* W_hh_enc = (const float*)d_in[3];
    const float* b_ih_enc = (const float*)d_in[4];
    const float* b_hh_enc = (const float*)d_in[5];
    const float* W_ih_dec = (const float*)d_in[6];
    const float* W_hh_dec = (const float*)d_in[7];
    const float* b_ih_dec = (const float*)d_in[8];
    const float* b_hh_dec = (const float*)d_in[9];
    const float* W_mu     = (const float*)d_in[10];
    const float* b_mu     = (const float*)d_in[11];
    const float* W_ls     = (const float*)d_in[12];
    const float* b_ls     = (const float*)d_in[13];
    const float* W_wr     = (const float*)d_in[14];
    const float* b_wr     = (const float*)d_in[15];
    const float* W_ra     = (const float*)d_in[16];
    const float* b_ra     = (const float*)d_in[17];
    const float* W_wa     = (const float*)d_in[18];
    const float* b_wa     = (const float*)d_in[19];

    float* rec = (float*)d_out;

    float* ws = (float*)d_ws;
    float* h_enc  = ws;  ws += BATCHN*HDIM;
    float* h_dec  = ws;  ws += BATCHN*HDIM;
    float* s_last = ws;  ws += IMGSZ;
    float* enc_in = ws;  ws += BATCHN*ENCIN;
    float* Pi     = ws;  ws += (size_t)SPLITK*BATCHN*G3;
    float* Ph     = ws;  ws += (size_t)SPLITK*BATCHN*G3;
    float* zbuf   = ws;  ws += BATCHN*ZDIM;
    float* Pw     = Pi;  // alias: Pw not live at same time as Pi

    hipMemsetAsync(rec,   0, (size_t)BATCHN*IMGSZ*sizeof(float), stream);
    hipMemsetAsync(h_enc, 0, (size_t)BATCHN*HDIM*sizeof(float), stream);
    hipMemsetAsync(h_dec, 0, (size_t)BATCHN*HDIM*sizeof(float), stream);
    init_slast_k<<<IMGSZ/256,256,0,stream>>>(s_last);

    for(int t=0;t<16;t++){
        // ---- read attention (params+filterbank fused) ----
        read_attn_k<<<BATCHN,256,0,stream>>>(x, s_last, h_dec, W_ra, b_ra, enc_in);
        // ---- encoder GRU: both GEMMs in one split-K kernel ----
        gemm_gru_splitk<<<dim3(G3/64, BATCHN/64, SPLITK),256,0,stream>>>(
            enc_in, W_ih_enc, ENCIN, h_enc, W_hh_enc, HDIM, Pi, Ph, G3);
        gru_combine_k<<<BATCHN*HDIM/256,256,0,stream>>>(Pi, Ph, b_ih_enc, b_hh_enc, h_enc);
        // ---- z sample ----
        z_k<<<BATCHN,256,0,stream>>>(h_enc, W_mu, b_mu, W_ls, b_ls, eps + (size_t)t*BATCHN*ZDIM, zbuf);
        // ---- decoder GRU ----
        gemm_gru_splitk<<<dim3(G3/64, BATCHN/64, SPLITK),256,0,stream>>>(
            zbuf, W_ih_dec, ZDIM, h_dec, W_hh_dec, HDIM, Pi, Ph, G3);
        gru_combine_k<<<BATCHN*HDIM/256,256,0,stream>>>(Pi, Ph, b_ih_dec, b_hh_dec, h_dec);
        // ---- write attention ----
        gemm_gru_splitk<<<dim3(1024/64, BATCHN/64, SPLITK),256,0,stream>>>(
            h_dec, W_wr, HDIM, (const float*)nullptr, (const float*)nullptr, 0, Pw, (float*)nullptr, 1024);
        write_apply_k<<<BATCHN,256,0,stream>>>(Pw, b_wr, h_dec, W_wa, b_wa, rec, s_last);
    }
    sigmoid_all_k<<<BATCHN*IMGSZ/256,256,0,stream>>>(rec);
}

// Round 3
// 2418.406 us; speedup vs baseline: 2.7172x; 1.5992x over previous
//
#include <hip/hip_runtime.h>
#include <math.h>

#define BATCHN 256
#define HDIM 512
#define ZDIM 128
#define NGRID 32
#define ABDIM 128
#define IMGSZ 16384   // 128*128
#define ENCIN 2560
#define G3 1536
#define SPLITK 4

__device__ __forceinline__ float sigmoidf_(float x){ return 1.0f/(1.0f+expf(-x)); }

__global__ void init_slast_k(float* __restrict__ s_last){
    int i = blockIdx.x*256 + threadIdx.x;
    s_last[i] = 0.5f;   // sigmoid(0)
}

// ---- attention params with NT=512 threads; pp[0..4] = raw p vector ----
__device__ __forceinline__ void attn_params_dev512(const float* __restrict__ h,
        const float* __restrict__ W, const float* __restrict__ bvec,
        float* red5 /*[5*8]*/, float* pp /*[8]*/, int tid){
    float accp[5];
    #pragma unroll
    for(int i=0;i<5;i++) accp[i]=0.f;
    for(int k=tid;k<HDIM;k+=512){
        float hv = h[k];
        #pragma unroll
        for(int i=0;i<5;i++) accp[i] += hv*W[i*HDIM+k];
    }
    int wv = tid>>6;
    #pragma unroll
    for(int i=0;i<5;i++){
        float a = accp[i];
        #pragma unroll
        for(int o=32;o>0;o>>=1) a += __shfl_down(a,o);
        if((tid&63)==0) red5[i*8+wv]=a;
    }
    __syncthreads();
    if(tid<5){
        float s = bvec[tid];
        #pragma unroll
        for(int w2=0;w2<8;w2++) s += red5[tid*8+w2];
        pp[tid]=s;
    }
    __syncthreads();
}

// transposed fill: fxT[pix][j], fyT[pix][j]  (each [128][32]); NT=512
__device__ __forceinline__ void fill_fb_T(float* fxT, float* fyT, const float* pp, int tid){
    float gx = 64.5f*(pp[0]+1.0f);
    float gy = 64.5f*(pp[1]+1.0f);
    float tss = 2.0f*expf(pp[2]);
    float delta = (127.0f/31.0f)*expf(pp[3]);
    int rr = tid>>3;        // 0..63 ; <32 -> Fx row j, else Fy row j-32
    int q  = tid&7;         // eighth of 128 pixels
    int j  = rr&31;
    bool isY = rr>=32;
    float mu = (isY?gy:gx) + ((float)j-15.5f)*delta;
    float v[16]; float s=0.f;
    #pragma unroll
    for(int i=0;i<16;i++){
        float d = (float)(q*16+i)-mu;
        float e = expf(-d*d/tss);
        v[i]=e; s+=e;
    }
    s += __shfl_xor(s,1); s += __shfl_xor(s,2); s += __shfl_xor(s,4);
    float inv = 1.0f/fmaxf(s,1e-8f);
    float* dst = isY? fyT : fxT;
    #pragma unroll
    for(int i=0;i<16;i++) dst[(q*16+i)*32 + j] = v[i]*inv;
    __syncthreads();
}

// row-major fill: fx[32][129], fy[32][129]; NT=512
__device__ __forceinline__ void fill_fb_R(float (*fx)[ABDIM+1], float (*fy)[ABDIM+1], const float* pp, int tid){
    float gx = 64.5f*(pp[0]+1.0f);
    float gy = 64.5f*(pp[1]+1.0f);
    float tss = 2.0f*expf(pp[2]);
    float delta = (127.0f/31.0f)*expf(pp[3]);
    int rr = tid>>3;
    int q  = tid&7;
    int j  = rr&31;
    bool isY = rr>=32;
    float mu = (isY?gy:gx) + ((float)j-15.5f)*delta;
    float v[16]; float s=0.f;
    #pragma unroll
    for(int i=0;i<16;i++){
        float d = (float)(q*16+i)-mu;
        float e = expf(-d*d/tss);
        v[i]=e; s+=e;
    }
    s += __shfl_xor(s,1); s += __shfl_xor(s,2); s += __shfl_xor(s,4);
    float inv = 1.0f/fmaxf(s,1e-8f);
    float* rowp = isY? &fy[j][0] : &fx[j][0];
    #pragma unroll
    for(int i=0;i<16;i++) rowp[q*16+i] = v[i]*inv;
    __syncthreads();
}

// per-batch fused read attention; 512 threads
// enc_in = [g*x_attn, g*xh_attn, h_dec]
__global__ __launch_bounds__(512) void read_attn_k(const float* __restrict__ xf, const float* __restrict__ s_last,
        const float* __restrict__ hdec, const float* __restrict__ W_ra, const float* __restrict__ b_ra,
        float* __restrict__ enc_in){
    // LDS layout: [0:4096) sFxT[128][32] ; [4096:4096+8256) union{ sFyT[128][32] | tmp[2][32][129] } ; red5[40]; pp[8]
    __shared__ float smem[4096 + 8256 + 48];
    float* sFxT = smem;
    float* sFyT = smem + 4096;
    float* tmp  = smem + 4096;            // aliases sFyT (barrier-separated)
    float* red5 = smem + 4096 + 8256;
    float* pp   = red5 + 40;
    int bb = blockIdx.x; int tid = threadIdx.x;
    const float* h = hdec + bb*HDIM;
    attn_params_dev512(h, W_ra, b_ra, red5, pp, tid);
    float gamma = expf(pp[4]);
    fill_fb_T(sFxT, sFyT, pp, tid);

    const float* img = xf + (size_t)bb*IMGSZ;
    int c = tid & 127;
    int jg = tid >> 7;     // 0..3 -> j = jg*8 .. jg*8+7
    float acc0[8], accS[8];
    #pragma unroll
    for(int i=0;i<8;i++){ acc0[i]=0.f; accS[i]=0.f; }
    for(int k=0;k<ABDIM;k++){
        float s  = img[k*ABDIM + c];
        float sl = s_last[k*ABDIM + c];
        float4 f0 = *(const float4*)&sFyT[k*32 + jg*8];
        float4 f1 = *(const float4*)&sFyT[k*32 + jg*8 + 4];
        acc0[0]+=f0.x*s;  acc0[1]+=f0.y*s;  acc0[2]+=f0.z*s;  acc0[3]+=f0.w*s;
        acc0[4]+=f1.x*s;  acc0[5]+=f1.y*s;  acc0[6]+=f1.z*s;  acc0[7]+=f1.w*s;
        accS[0]+=f0.x*sl; accS[1]+=f0.y*sl; accS[2]+=f0.z*sl; accS[3]+=f0.w*sl;
        accS[4]+=f1.x*sl; accS[5]+=f1.y*sl; accS[6]+=f1.z*sl; accS[7]+=f1.w*sl;
    }
    __syncthreads();          // everyone done reading sFyT
    #pragma unroll
    for(int i=0;i<8;i++){
        int j = jg*8+i;
        tmp[0*32*129 + j*129 + c] = acc0[i];
        tmp[1*32*129 + j*129 + c] = acc0[i] - accS[i];
    }
    __syncthreads();
    // stage 2: out[p][j][i] = gamma * sum_c tmp[p][j][c]*sFxT[c][i]
    {
        int i4 = tid & 7;            // i = i4*4 .. +3
        int j  = (tid>>3) & 31;
        int p  = tid >> 8;           // 0 or 1
        float a0=0.f,a1=0.f,a2=0.f,a3=0.f;
        for(int cc=0; cc<ABDIM; cc++){
            float tv = tmp[p*32*129 + j*129 + cc];
            float4 fx = *(const float4*)&sFxT[cc*32 + i4*4];
            a0 += tv*fx.x; a1 += tv*fx.y; a2 += tv*fx.z; a3 += tv*fx.w;
        }
        float4 o; o.x=gamma*a0; o.y=gamma*a1; o.z=gamma*a2; o.w=gamma*a3;
        *(float4*)(enc_in + (size_t)bb*ENCIN + p*1024 + j*NGRID + i4*4) = o;
    }
    for(int i=tid;i<HDIM;i+=512) enc_in[(size_t)bb*ENCIN + 2048 + i] = hdec[bb*HDIM + i];
}

// split-K GEMM for GRU: Pi[s] = A1@W1^T chunk, Ph[s] = A2@W2^T chunk
__global__ __launch_bounds__(256) void gemm_gru_splitk(const float* __restrict__ A1, const float* __restrict__ W1, int K1,
        const float* __restrict__ A2, const float* __restrict__ W2, int K2,
        float* __restrict__ Pi, float* __restrict__ Ph, int Nn){
    __shared__ float As[16][68];
    __shared__ float Bs[16][68];
    int tid = threadIdx.x;
    int row0 = blockIdx.y*64, col0 = blockIdx.x*64;
    int s = blockIdx.z;
    int tx = tid & 15, ty = tid >> 4;
    int lr = tid >> 2, lc = (tid & 3)*4;
    int ch1 = K1/SPLITK, ch2 = K2/SPLITK;
    float acc_i[4][4] = {{0.f}};
    float acc_h[4][4] = {{0.f}};
    for(int k0=s*ch1; k0<s*ch1+ch1; k0+=16){
        float4 av = *(const float4*)(A1 + (size_t)(row0+lr)*K1 + k0 + lc);
        float4 wv = *(const float4*)(W1 + (size_t)(col0+lr)*K1 + k0 + lc);
        As[lc+0][lr]=av.x; As[lc+1][lr]=av.y; As[lc+2][lr]=av.z; As[lc+3][lr]=av.w;
        Bs[lc+0][lr]=wv.x; Bs[lc+1][lr]=wv.y; Bs[lc+2][lr]=wv.z; Bs[lc+3][lr]=wv.w;
        __syncthreads();
        #pragma unroll
        for(int kk=0;kk<16;kk++){
            float4 a4 = *(const float4*)&As[kk][ty*4];
            float4 b4 = *(const float4*)&Bs[kk][tx*4];
            float av_[4] = {a4.x,a4.y,a4.z,a4.w};
            float bv_[4] = {b4.x,b4.y,b4.z,b4.w};
            #pragma unroll
            for(int i=0;i<4;i++)
                #pragma unroll
                for(int jj=0;jj<4;jj++) acc_i[i][jj] += av_[i]*bv_[jj];
        }
        __syncthreads();
    }
    if(K2>0){
        for(int k0=s*ch2; k0<s*ch2+ch2; k0+=16){
            float4 av = *(const float4*)(A2 + (size_t)(row0+lr)*K2 + k0 + lc);
            float4 wv = *(const float4*)(W2 + (size_t)(col0+lr)*K2 + k0 + lc);
            As[lc+0][lr]=av.x; As[lc+1][lr]=av.y; As[lc+2][lr]=av.z; As[lc+3][lr]=av.w;
            Bs[lc+0][lr]=wv.x; Bs[lc+1][lr]=wv.y; Bs[lc+2][lr]=wv.z; Bs[lc+3][lr]=wv.w;
            __syncthreads();
            #pragma unroll
            for(int kk=0;kk<16;kk++){
                float4 a4 = *(const float4*)&As[kk][ty*4];
                float4 b4 = *(const float4*)&Bs[kk][tx*4];
                float av_[4] = {a4.x,a4.y,a4.z,a4.w};
                float bv_[4] = {b4.x,b4.y,b4.z,b4.w};
                #pragma unroll
                for(int i=0;i<4;i++)
                    #pragma unroll
                    for(int jj=0;jj<4;jj++) acc_h[i][jj] += av_[i]*bv_[jj];
            }
            __syncthreads();
        }
    }
    #pragma unroll
    for(int i=0;i<4;i++){
        float4 o;
        o.x=acc_i[i][0]; o.y=acc_i[i][1]; o.z=acc_i[i][2]; o.w=acc_i[i][3];
        *(float4*)(Pi + ((size_t)s*BATCHN + row0+ty*4+i)*Nn + col0 + tx*4) = o;
    }
    if(K2>0){
        #pragma unroll
        for(int i=0;i<4;i++){
            float4 o;
            o.x=acc_h[i][0]; o.y=acc_h[i][1]; o.z=acc_h[i][2]; o.w=acc_h[i][3];
            *(float4*)(Ph + ((size_t)s*BATCHN + row0+ty*4+i)*Nn + col0 + tx*4) = o;
        }
    }
}

// reduce partials + biases + GRU gates; h = (1-z)*n + z*h
__global__ void gru_combine_k(const float* __restrict__ Pi, const float* __restrict__ Ph,
        const float* __restrict__ bi, const float* __restrict__ bh, float* __restrict__ h){
    int idx = blockIdx.x*256 + threadIdx.x;       // 256*512
    int bb = idx >> 9, j = idx & 511;
    float gi_r=0,gi_z=0,gi_n=0,gh_r=0,gh_z=0,gh_n=0;
    #pragma unroll
    for(int s=0;s<SPLITK;s++){
        size_t base = ((size_t)s*BATCHN + bb)*G3 + j;
        gi_r += Pi[base]; gi_z += Pi[base+512]; gi_n += Pi[base+1024];
        gh_r += Ph[base]; gh_z += Ph[base+512]; gh_n += Ph[base+1024];
    }
    gi_r += bi[j];      gh_r += bh[j];
    gi_z += bi[512+j];  gh_z += bh[512+j];
    gi_n += bi[1024+j]; gh_n += bh[1024+j];
    float r = sigmoidf_(gi_r + gh_r);
    float z = sigmoidf_(gi_z + gh_z);
    float n = tanhf(gi_n + r*gh_n);
    h[idx] = (1.f - z)*n + z*h[idx];
}

// z = (h@Wmu^T+bmu) + eps_t * exp(h@Wls^T+bls)
__global__ __launch_bounds__(256) void z_k(const float* __restrict__ henc, const float* __restrict__ Wmu,
        const float* __restrict__ bmu, const float* __restrict__ Wls, const float* __restrict__ bls,
        const float* __restrict__ eps_t, float* __restrict__ z){
    __shared__ float hs[HDIM];
    int bb = blockIdx.x, tid = threadIdx.x;
    int lane = tid&63, wv = tid>>6;
    for(int i=tid;i<HDIM;i+=256) hs[i]=henc[(size_t)bb*HDIM+i];
    __syncthreads();
    for(int it=0; it<32; ++it){
        int j = wv*32 + it;
        float am=0.f, al=0.f;
        for(int k=lane;k<HDIM;k+=64){
            float hv=hs[k];
            am += hv*Wmu[(size_t)j*HDIM+k];
            al += hv*Wls[(size_t)j*HDIM+k];
        }
        #pragma unroll
        for(int o=32;o>0;o>>=1){ am += __shfl_down(am,o); al += __shfl_down(al,o); }
        if(lane==0){
            float mu = am + bmu[j];
            float sg = expf(al + bls[j]);
            z[(size_t)bb*ZDIM + j] = mu + eps_t[(size_t)bb*ZDIM + j]*sg;
        }
    }
}

// write path: params+filterbank+reduce(Pw)+apply; refresh s_last from batch 255; 512 threads
__global__ __launch_bounds__(512) void write_apply_k(const float* __restrict__ Pw, const float* __restrict__ b_wr,
        const float* __restrict__ hdec, const float* __restrict__ W_wa, const float* __restrict__ b_wa,
        float* __restrict__ rec, float* __restrict__ s_last){
    __shared__ float sFy[NGRID][ABDIM+1];
    __shared__ float sFx[NGRID][ABDIM+1];
    __shared__ float sw[NGRID][36];
    __shared__ float t[ABDIM][36];
    __shared__ float red5[40];
    __shared__ float pp[8];
    int bb = blockIdx.x, tid = threadIdx.x;
    const float* h = hdec + bb*HDIM;
    attn_params_dev512(h, W_wa, b_wa, red5, pp, tid);
    float invg = expf(-pp[4]);
    fill_fb_R(sFx, sFy, pp, tid);
    for(int i=tid;i<NGRID*NGRID;i+=512){
        float a = b_wr[i];
        #pragma unroll
        for(int s=0;s<SPLITK;s++) a += Pw[((size_t)s*BATCHN + bb)*1024 + i];
        sw[i>>5][i&31] = a;
    }
    __syncthreads();
    // stage A: t[p][i] = sum_j sFy[j][p]*sw[j][i] ; thread: p = tid>>2, i = (tid&3)*8 ..+7
    {
        int p = tid>>2, iq = tid&3;
        float a[8];
        #pragma unroll
        for(int i=0;i<8;i++) a[i]=0.f;
        for(int j=0;j<NGRID;j++){
            float fy = sFy[j][p];
            float4 w0 = *(const float4*)&sw[j][iq*8];
            float4 w1 = *(const float4*)&sw[j][iq*8+4];
            a[0]+=fy*w0.x; a[1]+=fy*w0.y; a[2]+=fy*w0.z; a[3]+=fy*w0.w;
            a[4]+=fy*w1.x; a[5]+=fy*w1.y; a[6]+=fy*w1.z; a[7]+=fy*w1.w;
        }
        float4 o0; o0.x=a[0];o0.y=a[1];o0.z=a[2];o0.w=a[3];
        float4 o1; o1.x=a[4];o1.y=a[5];o1.z=a[6];o1.w=a[7];
        *(float4*)&t[p][iq*8]   = o0;
        *(float4*)&t[p][iq*8+4] = o1;
    }
    __syncthreads();
    // stage B: rec[p][q] += invg * sum_i t[p][i]*sFx[i][q] ; thread: q=tid&127, p in [pg*32, pg*32+32)
    {
        int q = tid&127, pg = tid>>7;
        float fxc[32];
        #pragma unroll
        for(int i=0;i<32;i++) fxc[i] = sFx[i][q];
        for(int pi=0; pi<32; pi++){
            int p = pg*32 + pi;
            float acc = 0.f;
            #pragma unroll
            for(int i4=0;i4<8;i4++){
                float4 tv = *(const float4*)&t[p][i4*4];
                acc += tv.x*fxc[i4*4] + tv.y*fxc[i4*4+1] + tv.z*fxc[i4*4+2] + tv.w*fxc[i4*4+3];
            }
            size_t off = (size_t)bb*IMGSZ + p*ABDIM + q;
            float nv = rec[off] + acc*invg;
            rec[off] = nv;
            if(bb==BATCHN-1) s_last[p*ABDIM + q] = sigmoidf_(nv);
        }
    }
}

__global__ void sigmoid_all_k(float* __restrict__ rec){
    int i = blockIdx.x*256 + threadIdx.x;
    rec[i] = sigmoidf_(rec[i]);
}

extern "C" void kernel_launch(void* const* d_in, const int* in_sizes, int n_in,
                              void* d_out, int out_size, void* d_ws, size_t ws_size,
                              hipStream_t stream) {
    const float* x        = (const float*)d_in[0];
    const float* eps      = (const float*)d_in[1];
    const float* W_ih_enc = (const float*)d_in[2];
    const float* W_hh_enc = (const float*)d_in[3];
    const float* b_ih_enc = (const float*)d_in[4];
    const float* b_hh_enc = (const float*)d_in[5];
    const float* W_ih_dec = (const float*)d_in[6];
    const float* W_hh_dec = (const float*)d_in[7];
    const float* b_ih_dec = (const float*)d_in[8];
    const float* b_hh_dec = (const float*)d_in[9];
    const float* W_mu     = (const float*)d_in[10];
    const float* b_mu     = (const float*)d_in[11];
    const float* W_ls     = (const float*)d_in[12];
    const float* b_ls     = (const float*)d_in[13];
    const float* W_wr     = (const float*)d_in[14];
    const float* b_wr     = (const float*)d_in[15];
    const float* W_ra     = (const float*)d_in[16];
    const float* b_ra     = (const float*)d_in[17];
    const float* W_wa     = (const float*)d_in[18];
    const float* b_wa     = (const float*)d_in[19];

    float* rec = (float*)d_out;

    float* ws = (float*)d_ws;
    float* h_enc  = ws;  ws += BATCHN*HDIM;
    float* h_dec  = ws;  ws += BATCHN*HDIM;
    float* s_last = ws;  ws += IMGSZ;
    float* enc_in = ws;  ws += BATCHN*ENCIN;
    float* Pi     = ws;  ws += (size_t)SPLITK*BATCHN*G3;
    float* Ph     = ws;  ws += (size_t)SPLITK*BATCHN*G3;
    float* zbuf   = ws;  ws += BATCHN*ZDIM;
    float* Pw     = Pi;  // alias: Pw not live at same time as Pi

    hipMemsetAsync(rec,   0, (size_t)BATCHN*IMGSZ*sizeof(float), stream);
    hipMemsetAsync(h_enc, 0, (size_t)BATCHN*HDIM*sizeof(float), stream);
    hipMemsetAsync(h_dec, 0, (size_t)BATCHN*HDIM*sizeof(float), stream);
    init_slast_k<<<IMGSZ/256,256,0,stream>>>(s_last);

    for(int t=0;t<16;t++){
        read_attn_k<<<BATCHN,512,0,stream>>>(x, s_last, h_dec, W_ra, b_ra, enc_in);
        gemm_gru_splitk<<<dim3(G3/64, BATCHN/64, SPLITK),256,0,stream>>>(
            enc_in, W_ih_enc, ENCIN, h_enc, W_hh_enc, HDIM, Pi, Ph, G3);
        gru_combine_k<<<BATCHN*HDIM/256,256,0,stream>>>(Pi, Ph, b_ih_enc, b_hh_enc, h_enc);
        z_k<<<BATCHN,256,0,stream>>>(h_enc, W_mu, b_mu, W_ls, b_ls, eps + (size_t)t*BATCHN*ZDIM, zbuf);
        gemm_gru_splitk<<<dim3(G3/64, BATCHN/64, SPLITK),256,0,stream>>>(
            zbuf, W_ih_dec, ZDIM, h_dec, W_hh_dec, HDIM, Pi, Ph, G3);
        gru_combine_k<<<BATCHN*HDIM/256,256,0,stream>>>(Pi, Ph, b_ih_dec, b_hh_dec, h_dec);
        gemm_gru_splitk<<<dim3(1024/64, BATCHN/64, SPLITK),256,0,stream>>>(
            h_dec, W_wr, HDIM, (const float*)nullptr, (const float*)nullptr, 0, Pw, (float*)nullptr, 1024);
        write_apply_k<<<BATCHN,512,0,stream>>>(Pw, b_wr, h_dec, W_wa, b_wa, rec, s_last);
    }
    sigmoid_all_k<<<BATCHN*IMGSZ/256,256,0,stream>>>(rec);
}

// Round 4
// 1814.637 us; speedup vs baseline: 3.6213x; 1.3327x over previous
//
#include <hip/hip_runtime.h>
#include <math.h>

#define BATCHN 256
#define HDIM 512
#define ZDIM 128
#define NGRID 32
#define ABDIM 128
#define IMGSZ 16384   // 128*128
#define ENCIN 2560
#define G3 1536
#define SPLITK 4

typedef __attribute__((ext_vector_type(8))) short short8;
typedef __attribute__((ext_vector_type(4))) float f32x4;

__device__ __forceinline__ float sigmoidf_(float x){ return 1.0f/(1.0f+expf(-x)); }

__device__ __forceinline__ ushort f2bf_rne(float f){
    union{float f; uint u;} x; x.f=f;
    uint r = (x.u + 0x7FFFu + ((x.u>>16)&1u)) >> 16;
    return (ushort)r;
}
__device__ __forceinline__ float bf2f(ushort h){
    union{uint u; float f;} y; y.u = ((uint)h)<<16;
    return y.f;
}

__global__ void init_slast_k(float* __restrict__ s_last){
    int i = blockIdx.x*256 + threadIdx.x;
    s_last[i] = 0.5f;   // sigmoid(0)
}

// convert f32 weights -> bf16 hi/lo arrays (vector-4)
__global__ void conv_w_k(const float* __restrict__ W, ushort* __restrict__ Wh,
                         ushort* __restrict__ Wl, int n4){
    int i = blockIdx.x*256 + threadIdx.x;
    if(i>=n4) return;
    float4 v = ((const float4*)W)[i];
    float f[4] = {v.x, v.y, v.z, v.w};
    ushort h[4], l[4];
    #pragma unroll
    for(int j=0;j<4;j++){
        h[j] = f2bf_rne(f[j]);
        l[j] = f2bf_rne(f[j] - bf2f(h[j]));
    }
    ushort4 hv; hv.x=h[0]; hv.y=h[1]; hv.z=h[2]; hv.w=h[3];
    ushort4 lv; lv.x=l[0]; lv.y=l[1]; lv.z=l[2]; lv.w=l[3];
    ((ushort4*)Wh)[i] = hv;
    ((ushort4*)Wl)[i] = lv;
}

// ---- attention params with NT=512 threads; pp[0..4] = raw p vector ----
__device__ __forceinline__ void attn_params_dev512(const float* __restrict__ h,
        const float* __restrict__ W, const float* __restrict__ bvec,
        float* red5 /*[5*8]*/, float* pp /*[8]*/, int tid){
    float accp[5];
    #pragma unroll
    for(int i=0;i<5;i++) accp[i]=0.f;
    for(int k=tid;k<HDIM;k+=512){
        float hv = h[k];
        #pragma unroll
        for(int i=0;i<5;i++) accp[i] += hv*W[i*HDIM+k];
    }
    int wv = tid>>6;
    #pragma unroll
    for(int i=0;i<5;i++){
        float a = accp[i];
        #pragma unroll
        for(int o=32;o>0;o>>=1) a += __shfl_down(a,o);
        if((tid&63)==0) red5[i*8+wv]=a;
    }
    __syncthreads();
    if(tid<5){
        float s = bvec[tid];
        #pragma unroll
        for(int w2=0;w2<8;w2++) s += red5[tid*8+w2];
        pp[tid]=s;
    }
    __syncthreads();
}

// transposed fill: fxT[pix][j], fyT[pix][j]  (each [128][32]); NT=512
__device__ __forceinline__ void fill_fb_T(float* fxT, float* fyT, const float* pp, int tid){
    float gx = 64.5f*(pp[0]+1.0f);
    float gy = 64.5f*(pp[1]+1.0f);
    float tss = 2.0f*expf(pp[2]);
    float delta = (127.0f/31.0f)*expf(pp[3]);
    int rr = tid>>3;        // 0..63 ; <32 -> Fx row j, else Fy row j-32
    int q  = tid&7;         // eighth of 128 pixels
    int j  = rr&31;
    bool isY = rr>=32;
    float mu = (isY?gy:gx) + ((float)j-15.5f)*delta;
    float v[16]; float s=0.f;
    #pragma unroll
    for(int i=0;i<16;i++){
        float d = (float)(q*16+i)-mu;
        float e = expf(-d*d/tss);
        v[i]=e; s+=e;
    }
    s += __shfl_xor(s,1); s += __shfl_xor(s,2); s += __shfl_xor(s,4);
    float inv = 1.0f/fmaxf(s,1e-8f);
    float* dst = isY? fyT : fxT;
    #pragma unroll
    for(int i=0;i<16;i++) dst[(q*16+i)*32 + j] = v[i]*inv;
    __syncthreads();
}

// row-major fill: fx[32][129], fy[32][129]; NT=512
__device__ __forceinline__ void fill_fb_R(float (*fx)[ABDIM+1], float (*fy)[ABDIM+1], const float* pp, int tid){
    float gx = 64.5f*(pp[0]+1.0f);
    float gy = 64.5f*(pp[1]+1.0f);
    float tss = 2.0f*expf(pp[2]);
    float delta = (127.0f/31.0f)*expf(pp[3]);
    int rr = tid>>3;
    int q  = tid&7;
    int j  = rr&31;
    bool isY = rr>=32;
    float mu = (isY?gy:gx) + ((float)j-15.5f)*delta;
    float v[16]; float s=0.f;
    #pragma unroll
    for(int i=0;i<16;i++){
        float d = (float)(q*16+i)-mu;
        float e = expf(-d*d/tss);
        v[i]=e; s+=e;
    }
    s += __shfl_xor(s,1); s += __shfl_xor(s,2); s += __shfl_xor(s,4);
    float inv = 1.0f/fmaxf(s,1e-8f);
    float* rowp = isY? &fy[j][0] : &fx[j][0];
    #pragma unroll
    for(int i=0;i<16;i++) rowp[q*16+i] = v[i]*inv;
    __syncthreads();
}

// per-batch fused read attention; 512 threads
__global__ __launch_bounds__(512) void read_attn_k(const float* __restrict__ xf, const float* __restrict__ s_last,
        const float* __restrict__ hdec, const float* __restrict__ W_ra, const float* __restrict__ b_ra,
        float* __restrict__ enc_in){
    __shared__ float smem[4096 + 8256 + 48];
    float* sFxT = smem;
    float* sFyT = smem + 4096;
    float* tmp  = smem + 4096;            // aliases sFyT (barrier-separated)
    float* red5 = smem + 4096 + 8256;
    float* pp   = red5 + 40;
    int bb = blockIdx.x; int tid = threadIdx.x;
    const float* h = hdec + bb*HDIM;
    attn_params_dev512(h, W_ra, b_ra, red5, pp, tid);
    float gamma = expf(pp[4]);
    fill_fb_T(sFxT, sFyT, pp, tid);

    const float* img = xf + (size_t)bb*IMGSZ;
    int c = tid & 127;
    int jg = tid >> 7;     // 0..3 -> j = jg*8 .. jg*8+7
    float acc0[8], accS[8];
    #pragma unroll
    for(int i=0;i<8;i++){ acc0[i]=0.f; accS[i]=0.f; }
    for(int k=0;k<ABDIM;k++){
        float s  = img[k*ABDIM + c];
        float sl = s_last[k*ABDIM + c];
        float4 f0 = *(const float4*)&sFyT[k*32 + jg*8];
        float4 f1 = *(const float4*)&sFyT[k*32 + jg*8 + 4];
        acc0[0]+=f0.x*s;  acc0[1]+=f0.y*s;  acc0[2]+=f0.z*s;  acc0[3]+=f0.w*s;
        acc0[4]+=f1.x*s;  acc0[5]+=f1.y*s;  acc0[6]+=f1.z*s;  acc0[7]+=f1.w*s;
        accS[0]+=f0.x*sl; accS[1]+=f0.y*sl; accS[2]+=f0.z*sl; accS[3]+=f0.w*sl;
        accS[4]+=f1.x*sl; accS[5]+=f1.y*sl; accS[6]+=f1.z*sl; accS[7]+=f1.w*sl;
    }
    __syncthreads();
    #pragma unroll
    for(int i=0;i<8;i++){
        int j = jg*8+i;
        tmp[0*32*129 + j*129 + c] = acc0[i];
        tmp[1*32*129 + j*129 + c] = acc0[i] - accS[i];
    }
    __syncthreads();
    {
        int i4 = tid & 7;
        int j  = (tid>>3) & 31;
        int p  = tid >> 8;
        float a0=0.f,a1=0.f,a2=0.f,a3=0.f;
        for(int cc=0; cc<ABDIM; cc++){
            float tv = tmp[p*32*129 + j*129 + cc];
            float4 fx = *(const float4*)&sFxT[cc*32 + i4*4];
            a0 += tv*fx.x; a1 += tv*fx.y; a2 += tv*fx.z; a3 += tv*fx.w;
        }
        float4 o; o.x=gamma*a0; o.y=gamma*a1; o.z=gamma*a2; o.w=gamma*a3;
        *(float4*)(enc_in + (size_t)bb*ENCIN + p*1024 + j*NGRID + i4*4) = o;
    }
    for(int i=tid;i<HDIM;i+=512) enc_in[(size_t)bb*ENCIN + 2048 + i] = hdec[bb*HDIM + i];
}

// ---- one MFMA GEMM (split-bf16, 3 products) over a K chunk ----
// block: 256 thr, 64x64 tile; wave w -> 32x32 quadrant (2x2 frags of 16x16x32)
__device__ __forceinline__ void gemm_one_mfma(const float* __restrict__ A,
        const ushort* __restrict__ Wh, const ushort* __restrict__ Wl,
        int K, int s, int row0, int col0, int Nn, float* __restrict__ Out,
        ushort* Ah, ushort* Al, ushort* Bh, ushort* Bl, int tid){
    int lane = tid&63, w = tid>>6;
    int m0 = (w>>1)*32, n0 = (w&1)*32;
    int fr = lane&15, kq = (lane>>4)*8;
    int sr = tid>>2, sq = (tid&3)*8;
    int ch = K/SPLITK;
    f32x4 acc[2][2];
    #pragma unroll
    for(int i=0;i<2;i++)
        #pragma unroll
        for(int j=0;j<2;j++) acc[i][j] = (f32x4){0.f,0.f,0.f,0.f};

    for(int k0=s*ch; k0<(s+1)*ch; k0+=32){
        // load A 8 f32, convert to hi/lo bf16, pack
        float4 v0 = *(const float4*)(A + (size_t)(row0+sr)*K + k0 + sq);
        float4 v1 = *(const float4*)(A + (size_t)(row0+sr)*K + k0 + sq + 4);
        float fv[8] = {v0.x,v0.y,v0.z,v0.w,v1.x,v1.y,v1.z,v1.w};
        uint hp[4], lp[4];
        #pragma unroll
        for(int j=0;j<4;j++){
            ushort h0 = f2bf_rne(fv[2*j]);
            ushort h1 = f2bf_rne(fv[2*j+1]);
            ushort l0 = f2bf_rne(fv[2*j]   - bf2f(h0));
            ushort l1 = f2bf_rne(fv[2*j+1] - bf2f(h1));
            hp[j] = (uint)h0 | ((uint)h1<<16);
            lp[j] = (uint)l0 | ((uint)l1<<16);
        }
        // load B (pre-converted bf16 hi/lo), 8 elems each
        uint4 bh = *(const uint4*)(Wh + (size_t)(col0+sr)*K + k0 + sq);
        uint4 bl = *(const uint4*)(Wl + (size_t)(col0+sr)*K + k0 + sq);
        __syncthreads();   // previous iteration's frag reads complete
        uint4 ah; ah.x=hp[0]; ah.y=hp[1]; ah.z=hp[2]; ah.w=hp[3];
        uint4 al; al.x=lp[0]; al.y=lp[1]; al.z=lp[2]; al.w=lp[3];
        *(uint4*)&Ah[sr*40 + sq] = ah;
        *(uint4*)&Al[sr*40 + sq] = al;
        *(uint4*)&Bh[sr*40 + sq] = bh;
        *(uint4*)&Bl[sr*40 + sq] = bl;
        __syncthreads();
        short8 a_h[2], a_l[2], b_h[2], b_l[2];
        #pragma unroll
        for(int mf=0;mf<2;mf++){
            a_h[mf] = *(short8*)&Ah[(m0+mf*16+fr)*40 + kq];
            a_l[mf] = *(short8*)&Al[(m0+mf*16+fr)*40 + kq];
        }
        #pragma unroll
        for(int nf=0;nf<2;nf++){
            b_h[nf] = *(short8*)&Bh[(n0+nf*16+fr)*40 + kq];
            b_l[nf] = *(short8*)&Bl[(n0+nf*16+fr)*40 + kq];
        }
        #pragma unroll
        for(int mf=0;mf<2;mf++)
            #pragma unroll
            for(int nf=0;nf<2;nf++){
                acc[mf][nf] = __builtin_amdgcn_mfma_f32_16x16x32_bf16(a_h[mf], b_h[nf], acc[mf][nf], 0,0,0);
                acc[mf][nf] = __builtin_amdgcn_mfma_f32_16x16x32_bf16(a_h[mf], b_l[nf], acc[mf][nf], 0,0,0);
                acc[mf][nf] = __builtin_amdgcn_mfma_f32_16x16x32_bf16(a_l[mf], b_h[nf], acc[mf][nf], 0,0,0);
            }
    }
    // epilogue: C/D layout col=lane&15, row=(lane>>4)*4+reg
    int crow = (lane>>4)*4, ccol = lane&15;
    #pragma unroll
    for(int mf=0;mf<2;mf++)
        #pragma unroll
        for(int nf=0;nf<2;nf++)
            #pragma unroll
            for(int r=0;r<4;r++)
                Out[((size_t)s*BATCHN + row0+m0+mf*16+crow+r)*Nn + col0+n0+nf*16+ccol] = acc[mf][nf][r];
    __syncthreads();   // LDS safe for next use
}

// dual GEMM (GRU): Pi[s] = A1@W1^T chunk, Ph[s] = A2@W2^T chunk
__global__ __launch_bounds__(256) void gemm_mfma_dual(
        const float* __restrict__ A1, const ushort* __restrict__ W1h, const ushort* __restrict__ W1l, int K1,
        const float* __restrict__ A2, const ushort* __restrict__ W2h, const ushort* __restrict__ W2l, int K2,
        float* __restrict__ Pi, float* __restrict__ Ph, int Nn){
    __shared__ ushort Ah[64*40], Al[64*40], Bh[64*40], Bl[64*40];
    int tid = threadIdx.x;
    int row0 = blockIdx.y*64, col0 = blockIdx.x*64, s = blockIdx.z;
    gemm_one_mfma(A1, W1h, W1l, K1, s, row0, col0, Nn, Pi, Ah, Al, Bh, Bl, tid);
    if(K2>0)
        gemm_one_mfma(A2, W2h, W2l, K2, s, row0, col0, Nn, Ph, Ah, Al, Bh, Bl, tid);
}

// reduce partials + biases + GRU gates; h = (1-z)*n + z*h
__global__ void gru_combine_k(const float* __restrict__ Pi, const float* __restrict__ Ph,
        const float* __restrict__ bi, const float* __restrict__ bh, float* __restrict__ h){
    int idx = blockIdx.x*256 + threadIdx.x;       // 256*512
    int bb = idx >> 9, j = idx & 511;
    float gi_r=0,gi_z=0,gi_n=0,gh_r=0,gh_z=0,gh_n=0;
    #pragma unroll
    for(int s=0;s<SPLITK;s++){
        size_t base = ((size_t)s*BATCHN + bb)*G3 + j;
        gi_r += Pi[base]; gi_z += Pi[base+512]; gi_n += Pi[base+1024];
        gh_r += Ph[base]; gh_z += Ph[base+512]; gh_n += Ph[base+1024];
    }
    gi_r += bi[j];      gh_r += bh[j];
    gi_z += bi[512+j];  gh_z += bh[512+j];
    gi_n += bi[1024+j]; gh_n += bh[1024+j];
    float r = sigmoidf_(gi_r + gh_r);
    float z = sigmoidf_(gi_z + gh_z);
    float n = tanhf(gi_n + r*gh_n);
    h[idx] = (1.f - z)*n + z*h[idx];
}

// z = (h@Wmu^T+bmu) + eps_t * exp(h@Wls^T+bls)
__global__ __launch_bounds__(256) void z_k(const float* __restrict__ henc, const float* __restrict__ Wmu,
        const float* __restrict__ bmu, const float* __restrict__ Wls, const float* __restrict__ bls,
        const float* __restrict__ eps_t, float* __restrict__ z){
    __shared__ float hs[HDIM];
    int bb = blockIdx.x, tid = threadIdx.x;
    int lane = tid&63, wv = tid>>6;
    for(int i=tid;i<HDIM;i+=256) hs[i]=henc[(size_t)bb*HDIM+i];
    __syncthreads();
    for(int it=0; it<32; ++it){
        int j = wv*32 + it;
        float am=0.f, al=0.f;
        for(int k=lane;k<HDIM;k+=64){
            float hv=hs[k];
            am += hv*Wmu[(size_t)j*HDIM+k];
            al += hv*Wls[(size_t)j*HDIM+k];
        }
        #pragma unroll
        for(int o=32;o>0;o>>=1){ am += __shfl_down(am,o); al += __shfl_down(al,o); }
        if(lane==0){
            float mu = am + bmu[j];
            float sg = expf(al + bls[j]);
            z[(size_t)bb*ZDIM + j] = mu + eps_t[(size_t)bb*ZDIM + j]*sg;
        }
    }
}

// write path: params+filterbank+reduce(Pw)+apply; refresh s_last from batch 255; 512 threads
__global__ __launch_bounds__(512) void write_apply_k(const float* __restrict__ Pw, const float* __restrict__ b_wr,
        const float* __restrict__ hdec, const float* __restrict__ W_wa, const float* __restrict__ b_wa,
        float* __restrict__ rec, float* __restrict__ s_last){
    __shared__ float sFy[NGRID][ABDIM+1];
    __shared__ float sFx[NGRID][ABDIM+1];
    __shared__ float sw[NGRID][36];
    __shared__ float t[ABDIM][36];
    __shared__ float red5[40];
    __shared__ float pp[8];
    int bb = blockIdx.x, tid = threadIdx.x;
    const float* h = hdec + bb*HDIM;
    attn_params_dev512(h, W_wa, b_wa, red5, pp, tid);
    float invg = expf(-pp[4]);
    fill_fb_R(sFx, sFy, pp, tid);
    for(int i=tid;i<NGRID*NGRID;i+=512){
        float a = b_wr[i];
        #pragma unroll
        for(int s=0;s<SPLITK;s++) a += Pw[((size_t)s*BATCHN + bb)*1024 + i];
        sw[i>>5][i&31] = a;
    }
    __syncthreads();
    {
        int p = tid>>2, iq = tid&3;
        float a[8];
        #pragma unroll
        for(int i=0;i<8;i++) a[i]=0.f;
        for(int j=0;j<NGRID;j++){
            float fy = sFy[j][p];
            float4 w0 = *(const float4*)&sw[j][iq*8];
            float4 w1 = *(const float4*)&sw[j][iq*8+4];
            a[0]+=fy*w0.x; a[1]+=fy*w0.y; a[2]+=fy*w0.z; a[3]+=fy*w0.w;
            a[4]+=fy*w1.x; a[5]+=fy*w1.y; a[6]+=fy*w1.z; a[7]+=fy*w1.w;
        }
        float4 o0; o0.x=a[0];o0.y=a[1];o0.z=a[2];o0.w=a[3];
        float4 o1; o1.x=a[4];o1.y=a[5];o1.z=a[6];o1.w=a[7];
        *(float4*)&t[p][iq*8]   = o0;
        *(float4*)&t[p][iq*8+4] = o1;
    }
    __syncthreads();
    {
        int q = tid&127, pg = tid>>7;
        float fxc[32];
        #pragma unroll
        for(int i=0;i<32;i++) fxc[i] = sFx[i][q];
        for(int pi=0; pi<32; pi++){
            int p = pg*32 + pi;
            float acc = 0.f;
            #pragma unroll
            for(int i4=0;i4<8;i4++){
                float4 tv = *(const float4*)&t[p][i4*4];
                acc += tv.x*fxc[i4*4] + tv.y*fxc[i4*4+1] + tv.z*fxc[i4*4+2] + tv.w*fxc[i4*4+3];
            }
            size_t off = (size_t)bb*IMGSZ + p*ABDIM + q;
            float nv = rec[off] + acc*invg;
            rec[off] = nv;
            if(bb==BATCHN-1) s_last[p*ABDIM + q] = sigmoidf_(nv);
        }
    }
}

__global__ void sigmoid_all_k(float* __restrict__ rec){
    int i = blockIdx.x*256 + threadIdx.x;
    rec[i] = sigmoidf_(rec[i]);
}

extern "C" void kernel_launch(void* const* d_in, const int* in_sizes, int n_in,
                              void* d_out, int out_size, void* d_ws, size_t ws_size,
                              hipStream_t stream) {
    const float* x        = (const float*)d_in[0];
    const float* eps      = (const float*)d_in[1];
    const float* W_ih_enc = (const float*)d_in[2];
    const float* W_hh_enc = (const float*)d_in[3];
    const float* b_ih_enc = (const float*)d_in[4];
    const float* b_hh_enc = (const float*)d_in[5];
    const float* W_ih_dec = (const float*)d_in[6];
    const float* W_hh_dec = (const float*)d_in[7];
    const float* b_ih_dec = (const float*)d_in[8];
    const float* b_hh_dec = (const float*)d_in[9];
    const float* W_mu     = (const float*)d_in[10];
    const float* b_mu     = (const float*)d_in[11];
    const float* W_ls     = (const float*)d_in[12];
    const float* b_ls     = (const float*)d_in[13];
    const float* W_wr     = (const float*)d_in[14];
    const float* b_wr     = (const float*)d_in[15];
    const float* W_ra     = (const float*)d_in[16];
    const float* b_ra     = (const float*)d_in[17];
    const float* W_wa     = (const float*)d_in[18];
    const float* b_wa     = (const float*)d_in[19];

    float* rec = (float*)d_out;

    float* ws = (float*)d_ws;
    float* h_enc  = ws;  ws += BATCHN*HDIM;
    float* h_dec  = ws;  ws += BATCHN*HDIM;
    float* s_last = ws;  ws += IMGSZ;
    float* enc_in = ws;  ws += BATCHN*ENCIN;
    float* Pi     = ws;  ws += (size_t)SPLITK*BATCHN*G3;
    float* Ph     = ws;  ws += (size_t)SPLITK*BATCHN*G3;
    float* zbuf   = ws;  ws += BATCHN*ZDIM;
    float* Pw     = Pi;  // alias: Pw not live at same time as Pi

    // bf16 hi/lo weight mirrors (converted once per launch)
    ushort* us = (ushort*)ws;
    ushort* Wie_h = us; us += 1536*2560;
    ushort* Wie_l = us; us += 1536*2560;
    ushort* Whe_h = us; us += 1536*512;
    ushort* Whe_l = us; us += 1536*512;
    ushort* Wid_h = us; us += 1536*128;
    ushort* Wid_l = us; us += 1536*128;
    ushort* Whd_h = us; us += 1536*512;
    ushort* Whd_l = us; us += 1536*512;
    ushort* Wwr_h = us; us += 1024*512;
    ushort* Wwr_l = us; us += 1024*512;

    hipMemsetAsync(rec,   0, (size_t)BATCHN*IMGSZ*sizeof(float), stream);
    hipMemsetAsync(h_enc, 0, (size_t)BATCHN*HDIM*sizeof(float), stream);
    hipMemsetAsync(h_dec, 0, (size_t)BATCHN*HDIM*sizeof(float), stream);
    init_slast_k<<<IMGSZ/256,256,0,stream>>>(s_last);

    conv_w_k<<<(1536*2560/4+255)/256,256,0,stream>>>(W_ih_enc, Wie_h, Wie_l, 1536*2560/4);
    conv_w_k<<<(1536*512/4+255)/256,256,0,stream>>>(W_hh_enc, Whe_h, Whe_l, 1536*512/4);
    conv_w_k<<<(1536*128/4+255)/256,256,0,stream>>>(W_ih_dec, Wid_h, Wid_l, 1536*128/4);
    conv_w_k<<<(1536*512/4+255)/256,256,0,stream>>>(W_hh_dec, Whd_h, Whd_l, 1536*512/4);
    conv_w_k<<<(1024*512/4+255)/256,256,0,stream>>>(W_wr, Wwr_h, Wwr_l, 1024*512/4);

    for(int t=0;t<16;t++){
        read_attn_k<<<BATCHN,512,0,stream>>>(x, s_last, h_dec, W_ra, b_ra, enc_in);
        gemm_mfma_dual<<<dim3(G3/64, BATCHN/64, SPLITK),256,0,stream>>>(
            enc_in, Wie_h, Wie_l, ENCIN, h_enc, Whe_h, Whe_l, HDIM, Pi, Ph, G3);
        gru_combine_k<<<BATCHN*HDIM/256,256,0,stream>>>(Pi, Ph, b_ih_enc, b_hh_enc, h_enc);
        z_k<<<BATCHN,256,0,stream>>>(h_enc, W_mu, b_mu, W_ls, b_ls, eps + (size_t)t*BATCHN*ZDIM, zbuf);
        gemm_mfma_dual<<<dim3(G3/64, BATCHN/64, SPLITK),256,0,stream>>>(
            zbuf, Wid_h, Wid_l, ZDIM, h_dec, Whd_h, Whd_l, HDIM, Pi, Ph, G3);
        gru_combine_k<<<BATCHN*HDIM/256,256,0,stream>>>(Pi, Ph, b_ih_dec, b_hh_dec, h_dec);
        gemm_mfma_dual<<<dim3(1024/64, BATCHN/64, SPLITK),256,0,stream>>>(
            h_dec, Wwr_h, Wwr_l, HDIM, (const float*)nullptr, (const ushort*)nullptr, (const ushort*)nullptr, 0,
            Pw, (float*)nullptr, 1024);
        write_apply_k<<<BATCHN,512,0,stream>>>(Pw, b_wr, h_dec, W_wa, b_wa, rec, s_last);
    }
    sigmoid_all_k<<<BATCHN*IMGSZ/256,256,0,stream>>>(rec);
}

// Round 5
// 1694.335 us; speedup vs baseline: 3.8784x; 1.0710x over previous
//
#include <hip/hip_runtime.h>
#include <math.h>

#define BATCHN 256
#define HDIM 512
#define ZDIM 128
#define NGRID 32
#define ABDIM 128
#define IMGSZ 16384   // 128*128
#define ENCIN 2560
#define G3 1536
#define SPLITK 4

typedef __attribute__((ext_vector_type(8))) short short8;
typedef __attribute__((ext_vector_type(4))) float f32x4;

__device__ __forceinline__ float sigmoidf_(float x){ return 1.0f/(1.0f+expf(-x)); }

__device__ __forceinline__ ushort f2bf_rne(float f){
    union{float f; uint u;} x; x.f=f;
    uint r = (x.u + 0x7FFFu + ((x.u>>16)&1u)) >> 16;
    return (ushort)r;
}
__device__ __forceinline__ float bf2f(ushort h){
    union{uint u; float f;} y; y.u = ((uint)h)<<16;
    return y.f;
}

__global__ void init_slast_k(float* __restrict__ s_last){
    int i = blockIdx.x*256 + threadIdx.x;
    s_last[i] = 0.5f;   // sigmoid(0)
}

// convert f32 weights -> bf16 hi/lo arrays (vector-4)
__global__ void conv_w_k(const float* __restrict__ W, ushort* __restrict__ Wh,
                         ushort* __restrict__ Wl, int n4){
    int i = blockIdx.x*256 + threadIdx.x;
    if(i>=n4) return;
    float4 v = ((const float4*)W)[i];
    float f[4] = {v.x, v.y, v.z, v.w};
    ushort h[4], l[4];
    #pragma unroll
    for(int j=0;j<4;j++){
        h[j] = f2bf_rne(f[j]);
        l[j] = f2bf_rne(f[j] - bf2f(h[j]));
    }
    ushort4 hv; hv.x=h[0]; hv.y=h[1]; hv.z=h[2]; hv.w=h[3];
    ushort4 lv; lv.x=l[0]; lv.y=l[1]; lv.z=l[2]; lv.w=l[3];
    ((ushort4*)Wh)[i] = hv;
    ((ushort4*)Wl)[i] = lv;
}

// ---- attention params with NT=512 threads; pp[0..4] = raw p vector ----
__device__ __forceinline__ void attn_params_dev512(const float* __restrict__ h,
        const float* __restrict__ W, const float* __restrict__ bvec,
        float* red5 /*[5*8]*/, float* pp /*[8]*/, int tid){
    float accp[5];
    #pragma unroll
    for(int i=0;i<5;i++) accp[i]=0.f;
    for(int k=tid;k<HDIM;k+=512){
        float hv = h[k];
        #pragma unroll
        for(int i=0;i<5;i++) accp[i] += hv*W[i*HDIM+k];
    }
    int wv = tid>>6;
    #pragma unroll
    for(int i=0;i<5;i++){
        float a = accp[i];
        #pragma unroll
        for(int o=32;o>0;o>>=1) a += __shfl_down(a,o);
        if((tid&63)==0) red5[i*8+wv]=a;
    }
    __syncthreads();
    if(tid<5){
        float s = bvec[tid];
        #pragma unroll
        for(int w2=0;w2<8;w2++) s += red5[tid*8+w2];
        pp[tid]=s;
    }
    __syncthreads();
}

// transposed fill: fxT[pix][j], fyT[pix][j]  (each [128][32]); NT=512
__device__ __forceinline__ void fill_fb_T(float* fxT, float* fyT, const float* pp, int tid){
    float gx = 64.5f*(pp[0]+1.0f);
    float gy = 64.5f*(pp[1]+1.0f);
    float tss = 2.0f*expf(pp[2]);
    float delta = (127.0f/31.0f)*expf(pp[3]);
    int rr = tid>>3;
    int q  = tid&7;
    int j  = rr&31;
    bool isY = rr>=32;
    float mu = (isY?gy:gx) + ((float)j-15.5f)*delta;
    float v[16]; float s=0.f;
    #pragma unroll
    for(int i=0;i<16;i++){
        float d = (float)(q*16+i)-mu;
        float e = expf(-d*d/tss);
        v[i]=e; s+=e;
    }
    s += __shfl_xor(s,1); s += __shfl_xor(s,2); s += __shfl_xor(s,4);
    float inv = 1.0f/fmaxf(s,1e-8f);
    float* dst = isY? fyT : fxT;
    #pragma unroll
    for(int i=0;i<16;i++) dst[(q*16+i)*32 + j] = v[i]*inv;
    __syncthreads();
}

// row-major fill: fx[32][129], fy[32][129]; NT=512
__device__ __forceinline__ void fill_fb_R(float (*fx)[ABDIM+1], float (*fy)[ABDIM+1], const float* pp, int tid){
    float gx = 64.5f*(pp[0]+1.0f);
    float gy = 64.5f*(pp[1]+1.0f);
    float tss = 2.0f*expf(pp[2]);
    float delta = (127.0f/31.0f)*expf(pp[3]);
    int rr = tid>>3;
    int q  = tid&7;
    int j  = rr&31;
    bool isY = rr>=32;
    float mu = (isY?gy:gx) + ((float)j-15.5f)*delta;
    float v[16]; float s=0.f;
    #pragma unroll
    for(int i=0;i<16;i++){
        float d = (float)(q*16+i)-mu;
        float e = expf(-d*d/tss);
        v[i]=e; s+=e;
    }
    s += __shfl_xor(s,1); s += __shfl_xor(s,2); s += __shfl_xor(s,4);
    float inv = 1.0f/fmaxf(s,1e-8f);
    float* rowp = isY? &fy[j][0] : &fx[j][0];
    #pragma unroll
    for(int i=0;i<16;i++) rowp[q*16+i] = v[i]*inv;
    __syncthreads();
}

// per-batch fused read attention; 512 threads; writes enc_in as bf16 hi/lo
__global__ __launch_bounds__(512) void read_attn_k(const float* __restrict__ xf, const float* __restrict__ s_last,
        const float* __restrict__ hdec, const ushort* __restrict__ Hd_h, const ushort* __restrict__ Hd_l,
        const float* __restrict__ W_ra, const float* __restrict__ b_ra,
        ushort* __restrict__ Eh, ushort* __restrict__ El){
    __shared__ float smem[4096 + 8256 + 48];
    float* sFxT = smem;
    float* sFyT = smem + 4096;
    float* tmp  = smem + 4096;            // aliases sFyT (barrier-separated)
    float* red5 = smem + 4096 + 8256;
    float* pp   = red5 + 40;
    int bb = blockIdx.x; int tid = threadIdx.x;
    const float* h = hdec + bb*HDIM;
    attn_params_dev512(h, W_ra, b_ra, red5, pp, tid);
    float gamma = expf(pp[4]);
    fill_fb_T(sFxT, sFyT, pp, tid);

    const float* img = xf + (size_t)bb*IMGSZ;
    int c = tid & 127;
    int jg = tid >> 7;
    float acc0[8], accS[8];
    #pragma unroll
    for(int i=0;i<8;i++){ acc0[i]=0.f; accS[i]=0.f; }
    for(int k=0;k<ABDIM;k++){
        float s  = img[k*ABDIM + c];
        float sl = s_last[k*ABDIM + c];
        float4 f0 = *(const float4*)&sFyT[k*32 + jg*8];
        float4 f1 = *(const float4*)&sFyT[k*32 + jg*8 + 4];
        acc0[0]+=f0.x*s;  acc0[1]+=f0.y*s;  acc0[2]+=f0.z*s;  acc0[3]+=f0.w*s;
        acc0[4]+=f1.x*s;  acc0[5]+=f1.y*s;  acc0[6]+=f1.z*s;  acc0[7]+=f1.w*s;
        accS[0]+=f0.x*sl; accS[1]+=f0.y*sl; accS[2]+=f0.z*sl; accS[3]+=f0.w*sl;
        accS[4]+=f1.x*sl; accS[5]+=f1.y*sl; accS[6]+=f1.z*sl; accS[7]+=f1.w*sl;
    }
    __syncthreads();
    #pragma unroll
    for(int i=0;i<8;i++){
        int j = jg*8+i;
        tmp[0*32*129 + j*129 + c] = acc0[i];
        tmp[1*32*129 + j*129 + c] = acc0[i] - accS[i];
    }
    __syncthreads();
    {
        int i4 = tid & 7;
        int j  = (tid>>3) & 31;
        int p  = tid >> 8;
        float a0=0.f,a1=0.f,a2=0.f,a3=0.f;
        for(int cc=0; cc<ABDIM; cc++){
            float tv = tmp[p*32*129 + j*129 + cc];
            float4 fx = *(const float4*)&sFxT[cc*32 + i4*4];
            a0 += tv*fx.x; a1 += tv*fx.y; a2 += tv*fx.z; a3 += tv*fx.w;
        }
        float ov[4] = {gamma*a0, gamma*a1, gamma*a2, gamma*a3};
        ushort4 oh, ol;
        ushort hq;
        hq=f2bf_rne(ov[0]); oh.x=hq; ol.x=f2bf_rne(ov[0]-bf2f(hq));
        hq=f2bf_rne(ov[1]); oh.y=hq; ol.y=f2bf_rne(ov[1]-bf2f(hq));
        hq=f2bf_rne(ov[2]); oh.z=hq; ol.z=f2bf_rne(ov[2]-bf2f(hq));
        hq=f2bf_rne(ov[3]); oh.w=hq; ol.w=f2bf_rne(ov[3]-bf2f(hq));
        size_t off = (size_t)bb*ENCIN + p*1024 + j*NGRID + i4*4;
        *(ushort4*)(Eh + off) = oh;
        *(ushort4*)(El + off) = ol;
    }
    // h_dec tail: copy from pre-converted mirrors
    {
        int i = tid;   // 0..511
        Eh[(size_t)bb*ENCIN + 2048 + i] = Hd_h[(size_t)bb*HDIM + i];
        El[(size_t)bb*ENCIN + 2048 + i] = Hd_l[(size_t)bb*HDIM + i];
    }
}

// ---- one MFMA GEMM (split-bf16, 3 products, pre-converted operands), BK=64 ----
__device__ __forceinline__ void gemm_one_bf(const ushort* __restrict__ Ah_g, const ushort* __restrict__ Al_g,
        const ushort* __restrict__ Wh, const ushort* __restrict__ Wl,
        int K, int s, int row0, int col0, int Nn, float* __restrict__ Out,
        ushort* Ah, ushort* Al, ushort* Bh, ushort* Bl, int tid){
    int lane = tid&63, w = tid>>6;
    int m0 = (w>>1)*32, n0 = (w&1)*32;
    int fr = lane&15, kq = (lane>>4)*8;
    int sr = tid>>2, sq = (tid&3)*16;
    int ch = K/SPLITK;
    int kend = (s+1)*ch;
    f32x4 acc[2][2];
    #pragma unroll
    for(int i=0;i<2;i++)
        #pragma unroll
        for(int j=0;j<2;j++) acc[i][j] = (f32x4){0.f,0.f,0.f,0.f};

    for(int k0=s*ch; k0<kend; k0+=64){
        int rem = kend - k0;
        uint4 vah0, vah1, val0, val1, vbh0, vbh1, vbl0, vbl1;
        bool gd = (sq < rem);
        if(gd){
            size_t aoff = (size_t)(row0+sr)*K + k0 + sq;
            size_t boff = (size_t)(col0+sr)*K + k0 + sq;
            vah0 = *(const uint4*)(Ah_g + aoff);
            vah1 = *(const uint4*)(Ah_g + aoff + 8);
            val0 = *(const uint4*)(Al_g + aoff);
            val1 = *(const uint4*)(Al_g + aoff + 8);
            vbh0 = *(const uint4*)(Wh + boff);
            vbh1 = *(const uint4*)(Wh + boff + 8);
            vbl0 = *(const uint4*)(Wl + boff);
            vbl1 = *(const uint4*)(Wl + boff + 8);
        }
        __syncthreads();   // previous iteration's frag reads complete
        if(gd){
            *(uint4*)&Ah[sr*72 + sq]     = vah0;
            *(uint4*)&Ah[sr*72 + sq + 8] = vah1;
            *(uint4*)&Al[sr*72 + sq]     = val0;
            *(uint4*)&Al[sr*72 + sq + 8] = val1;
            *(uint4*)&Bh[sr*72 + sq]     = vbh0;
            *(uint4*)&Bh[sr*72 + sq + 8] = vbh1;
            *(uint4*)&Bl[sr*72 + sq]     = vbl0;
            *(uint4*)&Bl[sr*72 + sq + 8] = vbl1;
        }
        __syncthreads();
        int nk = (rem>=64)?2:1;
        for(int ks=0; ks<nk; ks++){
            int kb = ks*32 + kq;
            short8 a_h[2], a_l[2], b_h[2], b_l[2];
            #pragma unroll
            for(int mf=0;mf<2;mf++){
                a_h[mf] = *(short8*)&Ah[(m0+mf*16+fr)*72 + kb];
                a_l[mf] = *(short8*)&Al[(m0+mf*16+fr)*72 + kb];
            }
            #pragma unroll
            for(int nf=0;nf<2;nf++){
                b_h[nf] = *(short8*)&Bh[(n0+nf*16+fr)*72 + kb];
                b_l[nf] = *(short8*)&Bl[(n0+nf*16+fr)*72 + kb];
            }
            #pragma unroll
            for(int mf=0;mf<2;mf++)
                #pragma unroll
                for(int nf=0;nf<2;nf++){
                    acc[mf][nf] = __builtin_amdgcn_mfma_f32_16x16x32_bf16(a_h[mf], b_h[nf], acc[mf][nf], 0,0,0);
                    acc[mf][nf] = __builtin_amdgcn_mfma_f32_16x16x32_bf16(a_h[mf], b_l[nf], acc[mf][nf], 0,0,0);
                    acc[mf][nf] = __builtin_amdgcn_mfma_f32_16x16x32_bf16(a_l[mf], b_h[nf], acc[mf][nf], 0,0,0);
                }
        }
    }
    int crow = (lane>>4)*4, ccol = lane&15;
    #pragma unroll
    for(int mf=0;mf<2;mf++)
        #pragma unroll
        for(int nf=0;nf<2;nf++)
            #pragma unroll
            for(int r=0;r<4;r++)
                Out[((size_t)s*BATCHN + row0+m0+mf*16+crow+r)*Nn + col0+n0+nf*16+ccol] = acc[mf][nf][r];
    __syncthreads();
}

__global__ __launch_bounds__(256) void gemm_bf_dual(
        const ushort* __restrict__ A1h, const ushort* __restrict__ A1l,
        const ushort* __restrict__ W1h, const ushort* __restrict__ W1l, int K1,
        const ushort* __restrict__ A2h, const ushort* __restrict__ A2l,
        const ushort* __restrict__ W2h, const ushort* __restrict__ W2l, int K2,
        float* __restrict__ Pi, float* __restrict__ Ph, int Nn){
    __shared__ ushort Ah[64*72], Al[64*72], Bh[64*72], Bl[64*72];
    int tid = threadIdx.x;
    int row0 = blockIdx.y*64, col0 = blockIdx.x*64, s = blockIdx.z;
    gemm_one_bf(A1h, A1l, W1h, W1l, K1, s, row0, col0, Nn, Pi, Ah, Al, Bh, Bl, tid);
    if(K2>0)
        gemm_one_bf(A2h, A2l, W2h, W2l, K2, s, row0, col0, Nn, Ph, Ah, Al, Bh, Bl, tid);
}

// encoder: reduce partials + gates -> h_enc (f32 + bf16 mirrors), then z sample -> bf16 mirrors
__global__ __launch_bounds__(512) void gru_combine_z_k(const float* __restrict__ Pi, const float* __restrict__ Ph,
        const float* __restrict__ bi, const float* __restrict__ bh,
        float* __restrict__ h, ushort* __restrict__ Hh, ushort* __restrict__ Hl,
        const float* __restrict__ Wmu, const float* __restrict__ bmu,
        const float* __restrict__ Wls, const float* __restrict__ bls,
        const float* __restrict__ eps_t, ushort* __restrict__ Zh, ushort* __restrict__ Zl){
    __shared__ float hs[HDIM];
    int bb = blockIdx.x, tid = threadIdx.x;   // 512
    int j = tid;
    float gi_r=bi[j], gi_z=bi[512+j], gi_n=bi[1024+j];
    float gh_r=bh[j], gh_z=bh[512+j], gh_n=bh[1024+j];
    #pragma unroll
    for(int s=0;s<SPLITK;s++){
        size_t base = ((size_t)s*BATCHN + bb)*G3 + j;
        gi_r += Pi[base]; gi_z += Pi[base+512]; gi_n += Pi[base+1024];
        gh_r += Ph[base]; gh_z += Ph[base+512]; gh_n += Ph[base+1024];
    }
    float r = sigmoidf_(gi_r + gh_r);
    float z = sigmoidf_(gi_z + gh_z);
    float n = tanhf(gi_n + r*gh_n);
    size_t hoff = (size_t)bb*HDIM + j;
    float hn = (1.f - z)*n + z*h[hoff];
    h[hoff] = hn; hs[j] = hn;
    ushort hh = f2bf_rne(hn);
    Hh[hoff] = hh; Hl[hoff] = f2bf_rne(hn - bf2f(hh));
    __syncthreads();
    // z sample: 4 lanes per output
    int jo = tid>>2, l4 = tid&3;
    float am=0.f, al_=0.f;
    for(int k=l4;k<HDIM;k+=4){
        float hv = hs[k];
        am  += hv*Wmu[(size_t)jo*HDIM+k];
        al_ += hv*Wls[(size_t)jo*HDIM+k];
    }
    am  += __shfl_xor(am,1);  am  += __shfl_xor(am,2);
    al_ += __shfl_xor(al_,1); al_ += __shfl_xor(al_,2);
    if(l4==0){
        float mu = am + bmu[jo];
        float sg = expf(al_ + bls[jo]);
        float zv = mu + eps_t[(size_t)bb*ZDIM + jo]*sg;
        ushort zh = f2bf_rne(zv);
        Zh[(size_t)bb*ZDIM + jo] = zh;
        Zl[(size_t)bb*ZDIM + jo] = f2bf_rne(zv - bf2f(zh));
    }
}

// decoder: reduce partials + gates -> h_dec (f32 + bf16 mirrors)
__global__ void gru_combine_bf_k(const float* __restrict__ Pi, const float* __restrict__ Ph,
        const float* __restrict__ bi, const float* __restrict__ bh,
        float* __restrict__ h, ushort* __restrict__ Hh, ushort* __restrict__ Hl){
    int idx = blockIdx.x*256 + threadIdx.x;
    int bb = idx >> 9, j = idx & 511;
    float gi_r=bi[j], gi_z=bi[512+j], gi_n=bi[1024+j];
    float gh_r=bh[j], gh_z=bh[512+j], gh_n=bh[1024+j];
    #pragma unroll
    for(int s=0;s<SPLITK;s++){
        size_t base = ((size_t)s*BATCHN + bb)*G3 + j;
        gi_r += Pi[base]; gi_z += Pi[base+512]; gi_n += Pi[base+1024];
        gh_r += Ph[base]; gh_z += Ph[base+512]; gh_n += Ph[base+1024];
    }
    float r = sigmoidf_(gi_r + gh_r);
    float z = sigmoidf_(gi_z + gh_z);
    float n = tanhf(gi_n + r*gh_n);
    float hn = (1.f - z)*n + z*h[idx];
    h[idx] = hn;
    ushort hh = f2bf_rne(hn);
    Hh[idx] = hh; Hl[idx] = f2bf_rne(hn - bf2f(hh));
}

// write path: params+filterbank+reduce(Pw)+apply; refresh s_last from batch 255; 512 threads
__global__ __launch_bounds__(512) void write_apply_k(const float* __restrict__ Pw, const float* __restrict__ b_wr,
        const float* __restrict__ hdec, const float* __restrict__ W_wa, const float* __restrict__ b_wa,
        float* __restrict__ rec, float* __restrict__ s_last){
    __shared__ float sFy[NGRID][ABDIM+1];
    __shared__ float sFx[NGRID][ABDIM+1];
    __shared__ float sw[NGRID][36];
    __shared__ float t[ABDIM][36];
    __shared__ float red5[40];
    __shared__ float pp[8];
    int bb = blockIdx.x, tid = threadIdx.x;
    const float* h = hdec + bb*HDIM;
    attn_params_dev512(h, W_wa, b_wa, red5, pp, tid);
    float invg = expf(-pp[4]);
    fill_fb_R(sFx, sFy, pp, tid);
    for(int i=tid;i<NGRID*NGRID;i+=512){
        float a = b_wr[i];
        #pragma unroll
        for(int s=0;s<SPLITK;s++) a += Pw[((size_t)s*BATCHN + bb)*1024 + i];
        sw[i>>5][i&31] = a;
    }
    __syncthreads();
    {
        int p = tid>>2, iq = tid&3;
        float a[8];
        #pragma unroll
        for(int i=0;i<8;i++) a[i]=0.f;
        for(int j=0;j<NGRID;j++){
            float fy = sFy[j][p];
            float4 w0 = *(const float4*)&sw[j][iq*8];
            float4 w1 = *(const float4*)&sw[j][iq*8+4];
            a[0]+=fy*w0.x; a[1]+=fy*w0.y; a[2]+=fy*w0.z; a[3]+=fy*w0.w;
            a[4]+=fy*w1.x; a[5]+=fy*w1.y; a[6]+=fy*w1.z; a[7]+=fy*w1.w;
        }
        float4 o0; o0.x=a[0];o0.y=a[1];o0.z=a[2];o0.w=a[3];
        float4 o1; o1.x=a[4];o1.y=a[5];o1.z=a[6];o1.w=a[7];
        *(float4*)&t[p][iq*8]   = o0;
        *(float4*)&t[p][iq*8+4] = o1;
    }
    __syncthreads();
    {
        int q = tid&127, pg = tid>>7;
        float fxc[32];
        #pragma unroll
        for(int i=0;i<32;i++) fxc[i] = sFx[i][q];
        for(int pi=0; pi<32; pi++){
            int p = pg*32 + pi;
            float acc = 0.f;
            #pragma unroll
            for(int i4=0;i4<8;i4++){
                float4 tv = *(const float4*)&t[p][i4*4];
                acc += tv.x*fxc[i4*4] + tv.y*fxc[i4*4+1] + tv.z*fxc[i4*4+2] + tv.w*fxc[i4*4+3];
            }
            size_t off = (size_t)bb*IMGSZ + p*ABDIM + q;
            float nv = rec[off] + acc*invg;
            rec[off] = nv;
            if(bb==BATCHN-1) s_last[p*ABDIM + q] = sigmoidf_(nv);
        }
    }
}

__global__ void sigmoid_all_k(float* __restrict__ rec){
    int i = blockIdx.x*256 + threadIdx.x;
    rec[i] = sigmoidf_(rec[i]);
}

extern "C" void kernel_launch(void* const* d_in, const int* in_sizes, int n_in,
                              void* d_out, int out_size, void* d_ws, size_t ws_size,
                              hipStream_t stream) {
    const float* x        = (const float*)d_in[0];
    const float* eps      = (const float*)d_in[1];
    const float* W_ih_enc = (const float*)d_in[2];
    const float* W_hh_enc = (const float*)d_in[3];
    const float* b_ih_enc = (const float*)d_in[4];
    const float* b_hh_enc = (const float*)d_in[5];
    const float* W_ih_dec = (const float*)d_in[6];
    const float* W_hh_dec = (const float*)d_in[7];
    const float* b_ih_dec = (const float*)d_in[8];
    const float* b_hh_dec = (const float*)d_in[9];
    const float* W_mu     = (const float*)d_in[10];
    const float* b_mu     = (const float*)d_in[11];
    const float* W_ls     = (const float*)d_in[12];
    const float* b_ls     = (const float*)d_in[13];
    const float* W_wr     = (const float*)d_in[14];
    const float* b_wr     = (const float*)d_in[15];
    const float* W_ra     = (const float*)d_in[16];
    const float* b_ra     = (const float*)d_in[17];
    const float* W_wa     = (const float*)d_in[18];
    const float* b_wa     = (const float*)d_in[19];

    float* rec = (float*)d_out;

    float* ws = (float*)d_ws;
    float* h_enc  = ws;  ws += BATCHN*HDIM;
    float* h_dec  = ws;  ws += BATCHN*HDIM;
    float* s_last = ws;  ws += IMGSZ;
    float* Pi     = ws;  ws += (size_t)SPLITK*BATCHN*G3;
    float* Ph     = ws;  ws += (size_t)SPLITK*BATCHN*G3;
    float* Pw     = Pi;  // alias: Pw not live at same time as Pi

    // bf16 hi/lo mirrors: weights (once) + activations (per step)
    ushort* us = (ushort*)ws;
    ushort* Wie_h = us; us += 1536*2560;
    ushort* Wie_l = us; us += 1536*2560;
    ushort* Whe_h = us; us += 1536*512;
    ushort* Whe_l = us; us += 1536*512;
    ushort* Wid_h = us; us += 1536*128;
    ushort* Wid_l = us; us += 1536*128;
    ushort* Whd_h = us; us += 1536*512;
    ushort* Whd_l = us; us += 1536*512;
    ushort* Wwr_h = us; us += 1024*512;
    ushort* Wwr_l = us; us += 1024*512;
    ushort* Eh    = us; us += BATCHN*ENCIN;
    ushort* El    = us; us += BATCHN*ENCIN;
    ushort* He_h  = us; us += BATCHN*HDIM;
    ushort* He_l  = us; us += BATCHN*HDIM;
    ushort* Hd_h  = us; us += BATCHN*HDIM;
    ushort* Hd_l  = us; us += BATCHN*HDIM;
    ushort* Zh    = us; us += BATCHN*ZDIM;
    ushort* Zl    = us; us += BATCHN*ZDIM;

    hipMemsetAsync(rec,   0, (size_t)BATCHN*IMGSZ*sizeof(float), stream);
    hipMemsetAsync(h_enc, 0, (size_t)BATCHN*HDIM*sizeof(float), stream);
    hipMemsetAsync(h_dec, 0, (size_t)BATCHN*HDIM*sizeof(float), stream);
    hipMemsetAsync(He_h,  0, (size_t)BATCHN*HDIM*sizeof(ushort)*2, stream);  // He_h+He_l contiguous
    hipMemsetAsync(Hd_h,  0, (size_t)BATCHN*HDIM*sizeof(ushort)*2, stream);  // Hd_h+Hd_l contiguous
    init_slast_k<<<IMGSZ/256,256,0,stream>>>(s_last);

    conv_w_k<<<(1536*2560/4+255)/256,256,0,stream>>>(W_ih_enc, Wie_h, Wie_l, 1536*2560/4);
    conv_w_k<<<(1536*512/4+255)/256,256,0,stream>>>(W_hh_enc, Whe_h, Whe_l, 1536*512/4);
    conv_w_k<<<(1536*128/4+255)/256,256,0,stream>>>(W_ih_dec, Wid_h, Wid_l, 1536*128/4);
    conv_w_k<<<(1536*512/4+255)/256,256,0,stream>>>(W_hh_dec, Whd_h, Whd_l, 1536*512/4);
    conv_w_k<<<(1024*512/4+255)/256,256,0,stream>>>(W_wr, Wwr_h, Wwr_l, 1024*512/4);

    for(int t=0;t<16;t++){
        read_attn_k<<<BATCHN,512,0,stream>>>(x, s_last, h_dec, Hd_h, Hd_l, W_ra, b_ra, Eh, El);
        gemm_bf_dual<<<dim3(G3/64, BATCHN/64, SPLITK),256,0,stream>>>(
            Eh, El, Wie_h, Wie_l, ENCIN, He_h, He_l, Whe_h, Whe_l, HDIM, Pi, Ph, G3);
        gru_combine_z_k<<<BATCHN,512,0,stream>>>(Pi, Ph, b_ih_enc, b_hh_enc,
            h_enc, He_h, He_l, W_mu, b_mu, W_ls, b_ls, eps + (size_t)t*BATCHN*ZDIM, Zh, Zl);
        gemm_bf_dual<<<dim3(G3/64, BATCHN/64, SPLITK),256,0,stream>>>(
            Zh, Zl, Wid_h, Wid_l, ZDIM, Hd_h, Hd_l, Whd_h, Whd_l, HDIM, Pi, Ph, G3);
        gru_combine_bf_k<<<BATCHN*HDIM/256,256,0,stream>>>(Pi, Ph, b_ih_dec, b_hh_dec, h_dec, Hd_h, Hd_l);
        gemm_bf_dual<<<dim3(1024/64, BATCHN/64, SPLITK),256,0,stream>>>(
            Hd_h, Hd_l, Wwr_h, Wwr_l, HDIM,
            (const ushort*)nullptr, (const ushort*)nullptr, (const ushort*)nullptr, (const ushort*)nullptr, 0,
            Pw, (float*)nullptr, 1024);
        write_apply_k<<<BATCHN,512,0,stream>>>(Pw, b_wr, h_dec, W_wa, b_wa, rec, s_last);
    }
    sigmoid_all_k<<<BATCHN*IMGSZ/256,256,0,stream>>>(rec);
}